// Round 2
// baseline (479.999 us; speedup 1.0000x reference)
//
#include <hip/hip_runtime.h>
#include <math.h>

typedef unsigned int uint32;
typedef __attribute__((ext_vector_type(8))) short bf16x8;
typedef __attribute__((ext_vector_type(4))) float f32x4;

__device__ __forceinline__ ushort f2bf(float f) {
  uint32 u = __builtin_bit_cast(uint32, f);
  uint32 r = (u + 0x7fff + ((u >> 16) & 1)) >> 16;  // RNE
  return (ushort)r;
}
__device__ __forceinline__ float bf_lo(uint32 u) {
  return __builtin_bit_cast(float, u << 16);
}
__device__ __forceinline__ float bf_hi(uint32 u) {
  return __builtin_bit_cast(float, u & 0xffff0000u);
}

// ---------------------------------------------------------------------------
// C[M,64] = A[M,K] @ W[64,K]^T via mfma_f32_16x16x32_bf16.
// Block: 256 thr (4 waves), tile 128 rows x 64 cols. W staged to LDS once
// (bf16, row stride 264), A staged per 32-k step (bf16, row stride 40).
// ---------------------------------------------------------------------------
template <bool BF16OUT>
__global__ __launch_bounds__(256) void gemm_mfma(const float* __restrict__ A,
                                                 const float* __restrict__ W,
                                                 float* __restrict__ C,
                                                 ushort* __restrict__ Cb,
                                                 int M, int K) {
  __shared__ __align__(16) ushort Ws[64 * 264];
  __shared__ __align__(16) ushort As[128 * 40];
  const int t = threadIdx.x;
  const int lane = t & 63;
  const int w = t >> 6;
  const int quad = lane >> 4;
  const int l16 = lane & 15;
  const int rBase = blockIdx.x * 128;

  // stage W[64][K] -> bf16 LDS (coalesced float4 reads)
  const int kq4 = K >> 2;
  for (int idx = t; idx < 64 * kq4; idx += 256) {
    int row = idx / kq4, kq = idx - row * kq4;
    float4 v = *(const float4*)(W + (size_t)row * K + kq * 4);
    ushort4 b;
    b.x = f2bf(v.x); b.y = f2bf(v.y); b.z = f2bf(v.z); b.w = f2bf(v.w);
    *(ushort4*)&Ws[row * 264 + kq * 4] = b;
  }

  f32x4 acc[2][4];
  #pragma unroll
  for (int i = 0; i < 2; ++i)
    #pragma unroll
    for (int n = 0; n < 4; ++n) acc[i][n] = (f32x4){0.f, 0.f, 0.f, 0.f};

  const int rStage = t >> 1;      // 0..127
  const int halfStage = t & 1;    // 0..1

  for (int kb = 0; kb < K; kb += 32) {
    {
      int gr = rBase + rStage;
      #pragma unroll
      for (int q = 0; q < 4; ++q) {
        int kk = kb + halfStage * 16 + q * 4;
        float4 v = make_float4(0.f, 0.f, 0.f, 0.f);
        if (gr < M) v = *(const float4*)(A + (size_t)gr * K + kk);
        ushort4 b;
        b.x = f2bf(v.x); b.y = f2bf(v.y); b.z = f2bf(v.z); b.w = f2bf(v.w);
        *(ushort4*)&As[rStage * 40 + halfStage * 16 + q * 4] = b;
      }
    }
    __syncthreads();

    bf16x8 afrag[2], bfrag[4];
    #pragma unroll
    for (int i = 0; i < 2; ++i)
      afrag[i] = *(const bf16x8*)&As[(w * 32 + i * 16 + l16) * 40 + quad * 8];
    #pragma unroll
    for (int n = 0; n < 4; ++n)
      bfrag[n] = *(const bf16x8*)&Ws[(n * 16 + l16) * 264 + kb + quad * 8];

    #pragma unroll
    for (int i = 0; i < 2; ++i)
      #pragma unroll
      for (int n = 0; n < 4; ++n)
        acc[i][n] = __builtin_amdgcn_mfma_f32_16x16x32_bf16(afrag[i], bfrag[n],
                                                            acc[i][n], 0, 0, 0);
    __syncthreads();
  }

  #pragma unroll
  for (int i = 0; i < 2; ++i)
    #pragma unroll
    for (int nt = 0; nt < 4; ++nt)
      #pragma unroll
      for (int r = 0; r < 4; ++r) {
        int row = rBase + w * 32 + i * 16 + quad * 4 + r;
        int col = nt * 16 + l16;
        if (row < M) {
          if (BF16OUT)
            Cb[(size_t)row * 64 + col] = f2bf(acc[i][nt][r]);
          else
            C[(size_t)row * 64 + col] = acc[i][nt][r];
        }
      }
}

// ---------------------------------------------------------------------------
// E-parallel CSR build: degree count (global atomics, low contention: ~16
// edges/node over 100K L2-resident counters) -> 3-level exclusive scan ->
// atomic-cursor scatter (edgeSrc target 6.4 MB, L2-resident).
// ---------------------------------------------------------------------------
__global__ __launch_bounds__(256) void deg_count(const int* __restrict__ dst,
                                                 int* __restrict__ deg, int E) {
  const int tid = blockIdx.x * blockDim.x + threadIdx.x;
  const int stride = gridDim.x * blockDim.x;
  const int E4 = E >> 2;
  const int4* __restrict__ d4 = (const int4*)dst;
  for (int i = tid; i < E4; i += stride) {
    int4 v = d4[i];
    atomicAdd(&deg[v.x], 1);
    atomicAdd(&deg[v.y], 1);
    atomicAdd(&deg[v.z], 1);
    atomicAdd(&deg[v.w], 1);
  }
  // tail
  for (int i = E4 * 4 + tid; i < E; i += stride) atomicAdd(&deg[dst[i]], 1);
}

// block scans 1024 elems (256 thr x 4); writes block-local exclusive into
// offsets and the block total into partials[b].
__global__ __launch_bounds__(256) void scan_part(const int* __restrict__ deg,
                                                 int* __restrict__ offsets,
                                                 int* __restrict__ partials, int N) {
  __shared__ int wsum[4];
  const int t = threadIdx.x;
  const int lane = t & 63, wave = t >> 6;
  const int i0 = blockIdx.x * 1024 + t * 4;
  int v[4];
  if (i0 + 3 < N) {
    int4 x = *(const int4*)(deg + i0);
    v[0] = x.x; v[1] = x.y; v[2] = x.z; v[3] = x.w;
  } else {
    #pragma unroll
    for (int k = 0; k < 4; ++k) v[k] = (i0 + k < N) ? deg[i0 + k] : 0;
  }
  int s = v[0] + v[1] + v[2] + v[3];
  int inc = s;
  #pragma unroll
  for (int d = 1; d < 64; d <<= 1) {
    int o = __shfl_up(inc, d, 64);
    if (lane >= d) inc += o;
  }
  if (lane == 63) wsum[wave] = inc;
  __syncthreads();
  int wbase = 0;
  #pragma unroll
  for (int w = 0; w < 4; ++w)
    if (w < wave) wbase += wsum[w];
  int run = wbase + inc - s;  // exclusive prefix of this thread's first elem
  if (i0 + 3 < N) {
    int4 o;
    o.x = run; o.y = run + v[0]; o.z = run + v[0] + v[1]; o.w = run + v[0] + v[1] + v[2];
    *(int4*)(offsets + i0) = o;
  } else {
    #pragma unroll
    for (int k = 0; k < 4; ++k) {
      if (i0 + k < N) offsets[i0 + k] = run;
      run += v[k];
    }
  }
  if (t == 255) partials[blockIdx.x] = wbase + inc;
}

// single block scans <=256 block totals (N <= 262144) into exclusive form.
__global__ __launch_bounds__(256) void scan_top(int* __restrict__ partials,
                                                int* __restrict__ offsets,
                                                int nparts, int N, int E) {
  __shared__ int wsum[4];
  const int t = threadIdx.x;
  const int lane = t & 63, wave = t >> 6;
  int x = (t < nparts) ? partials[t] : 0;
  int inc = x;
  #pragma unroll
  for (int d = 1; d < 64; d <<= 1) {
    int o = __shfl_up(inc, d, 64);
    if (lane >= d) inc += o;
  }
  if (lane == 63) wsum[wave] = inc;
  __syncthreads();
  int wbase = 0;
  #pragma unroll
  for (int w = 0; w < 4; ++w)
    if (w < wave) wbase += wsum[w];
  if (t < nparts) partials[t] = wbase + inc - x;
  if (t == 0) offsets[N] = E;
}

// add scanned block bases back; init scatter cursors.
__global__ __launch_bounds__(256) void scan_add(int* __restrict__ offsets,
                                                const int* __restrict__ partials,
                                                int* __restrict__ cursor, int N) {
  const int i = blockIdx.x * blockDim.x + threadIdx.x;
  if (i < N) {
    int v = offsets[i] + partials[i >> 10];
    offsets[i] = v;
    cursor[i] = v;
  }
}

__global__ __launch_bounds__(256) void scatter(const int* __restrict__ src,
                                               const int* __restrict__ dst,
                                               int* __restrict__ cursor,
                                               int* __restrict__ edgeSrc, int E) {
  const int tid = blockIdx.x * blockDim.x + threadIdx.x;
  const int stride = gridDim.x * blockDim.x;
  const int E4 = E >> 2;
  const int4* __restrict__ d4 = (const int4*)dst;
  const int4* __restrict__ s4 = (const int4*)src;
  for (int i = tid; i < E4; i += stride) {
    int4 dv = d4[i];
    int4 sv = s4[i];
    edgeSrc[atomicAdd(&cursor[dv.x], 1)] = sv.x;
    edgeSrc[atomicAdd(&cursor[dv.y], 1)] = sv.y;
    edgeSrc[atomicAdd(&cursor[dv.z], 1)] = sv.z;
    edgeSrc[atomicAdd(&cursor[dv.w], 1)] = sv.w;
  }
  for (int i = E4 * 4 + tid; i < E; i += stride)
    edgeSrc[atomicAdd(&cursor[dst[i]], 1)] = src[i];
}

// ---------------------------------------------------------------------------
// One wave per dst, fused single-gather softmax aggregation.
// Quarter-wave (16 lanes x 4 dims) per edge, 4 edges per step, blocks of 32
// edges. z[src] rows gathered ONCE into registers and reused for both the
// logit dot and the weighted accumulation.
// ---------------------------------------------------------------------------
__global__ __launch_bounds__(256) void aggregate(const ushort* __restrict__ zb,
                                                 const float* __restrict__ df,
                                                 const int* __restrict__ offsets,
                                                 const int* __restrict__ edgeSrc,
                                                 float* __restrict__ out, int N) {
  int gwave = (blockIdx.x * blockDim.x + threadIdx.x) >> 6;
  int lane = threadIdx.x & 63;
  if (gwave >= N) return;
  const int d = __builtin_amdgcn_readfirstlane(gwave);
  const int g = lane >> 4;    // quarter-wave group: one edge per group per step
  const int l16 = lane & 15;  // 4 contiguous dims per lane
  const int beg = offsets[d];
  const int end = offsets[d + 1];

  const float4 df4 = *(const float4*)(df + (size_t)d * 64 + l16 * 4);

  float m = -INFINITY, l = 0.f;
  float ax = 0.f, ay = 0.f, az = 0.f, aw = 0.f;  // per-group partial acc

  for (int j0 = beg; j0 < end; j0 += 32) {
    const int nst = min(8, (end - j0 + 3) >> 2);  // steps of 4 edges
    uint2 zf[8];   // gathered z frags, statically indexed (unrolled)
    float ew[8];   // e, overwritten in place by w
    float bm = -INFINITY;

    // phase 1: coalesced gather + cooperative dot (16-lane tree reduce)
    #pragma unroll
    for (int st = 0; st < 8; ++st) {
      if (st < nst) {
        const int eidx = j0 + st * 4 + g;  // group-uniform
        const bool act = eidx < end;       // group-uniform predicate
        int s = 0;
        if (act) s = edgeSrc[eidx];
        zf[st] = *(const uint2*)(zb + (size_t)s * 64 + l16 * 4);
        float p = bf_lo(zf[st].x) * df4.x;
        p = fmaf(bf_hi(zf[st].x), df4.y, p);
        p = fmaf(bf_lo(zf[st].y), df4.z, p);
        p = fmaf(bf_hi(zf[st].y), df4.w, p);
        p += __shfl_xor(p, 1, 64);
        p += __shfl_xor(p, 2, 64);
        p += __shfl_xor(p, 4, 64);
        p += __shfl_xor(p, 8, 64);
        ew[st] = act ? p : -INFINITY;
        bm = fmaxf(bm, ew[st]);
      }
    }
    bm = fmaxf(bm, __shfl_xor(bm, 16, 64));
    bm = fmaxf(bm, __shfl_xor(bm, 32, 64));

    const float nm = fmaxf(m, bm);
    const float alpha = __expf(m - nm);
    float sw = 0.f;
    #pragma unroll
    for (int st = 0; st < 8; ++st) {
      if (st < nst) {
        const float w = __expf(ew[st] - nm);  // -INF -> 0 for padded slots
        ew[st] = w;
        sw += w;
      }
    }
    sw += __shfl_xor(sw, 16, 64);
    sw += __shfl_xor(sw, 32, 64);
    l = l * alpha + sw;
    m = nm;

    ax *= alpha; ay *= alpha; az *= alpha; aw *= alpha;
    #pragma unroll
    for (int st = 0; st < 8; ++st) {
      if (st < nst) {
        const float w = ew[st];
        ax = fmaf(w, bf_lo(zf[st].x), ax);
        ay = fmaf(w, bf_hi(zf[st].x), ay);
        az = fmaf(w, bf_lo(zf[st].y), az);
        aw = fmaf(w, bf_hi(zf[st].y), aw);
      }
    }
  }

  ax += __shfl_xor(ax, 16, 64); ax += __shfl_xor(ax, 32, 64);
  ay += __shfl_xor(ay, 16, 64); ay += __shfl_xor(ay, 32, 64);
  az += __shfl_xor(az, 16, 64); az += __shfl_xor(az, 32, 64);
  aw += __shfl_xor(aw, 16, 64); aw += __shfl_xor(aw, 32, 64);

  if (lane < 16) {
    const float inv = (l > 0.f) ? (1.f / l) : 0.f;
    float4 o;
    o.x = ax * inv; o.y = ay * inv; o.z = az * inv; o.w = aw * inv;
    *(float4*)(out + (size_t)d * 64 + l16 * 4) = o;
  }
}

// ---------------------------------------------------------------------------
extern "C" void kernel_launch(void* const* d_in, const int* in_sizes, int n_in,
                              void* d_out, int out_size, void* d_ws, size_t ws_size,
                              hipStream_t stream) {
  const float* h     = (const float*)d_in[0];  // [N,256]
  const float* feat  = (const float*)d_in[1];  // [N,64]
  const float* W_fc  = (const float*)d_in[2];  // [64,256]
  const float* W_dst = (const float*)d_in[3];  // [64,64]
  const int*   src   = (const int*)d_in[4];    // [E]
  const int*   dst   = (const int*)d_in[5];    // [E]
  float* out = (float*)d_out;

  const int N = in_sizes[1] / 64;        // 100000
  const int E = in_sizes[4];             // 1600000
  const int IN_DIM = in_sizes[0] / N;    // 256

  // workspace layout (16B-aligned blocks)
  char* ws = (char*)d_ws;
  ushort* zb = (ushort*)ws;                        // N*64 bf16
  float* df = (float*)(zb + (size_t)N * 64);       // N*64 f32
  int* deg = (int*)(df + (size_t)N * 64);          // N (degree, then cursor)
  int* offsets = deg + N;                          // N+1
  int* edgeSrc = offsets + N + 1;                  // E
  int* partials = edgeSrc + E;                     // <=256

  hipMemsetAsync(deg, 0, sizeof(int) * (size_t)N, stream);

  int ggrid = (N + 127) / 128;  // 782
  gemm_mfma<true><<<ggrid, 256, 0, stream>>>(h, W_fc, nullptr, zb, N, IN_DIM);
  gemm_mfma<false><<<ggrid, 256, 0, stream>>>(feat, W_dst, df, nullptr, N, 64);

  const int nparts = (N + 1023) / 1024;  // 98 (<=256 required by scan_top)
  deg_count<<<1024, 256, 0, stream>>>(dst, deg, E);
  scan_part<<<nparts, 256, 0, stream>>>(deg, offsets, partials, N);
  scan_top<<<1, 256, 0, stream>>>(partials, offsets, nparts, N, E);
  scan_add<<<(N + 255) / 256, 256, 0, stream>>>(offsets, partials, deg, N);
  scatter<<<1024, 256, 0, stream>>>(src, dst, deg, edgeSrc, E);

  aggregate<<<(N + 3) / 4, 256, 0, stream>>>(zb, df, offsets, edgeSrc, out, N);
}

// Round 3
// 371.794 us; speedup vs baseline: 1.2910x; 1.2910x over previous
//
#include <hip/hip_runtime.h>
#include <math.h>

typedef unsigned int uint32;
typedef __attribute__((ext_vector_type(8))) short bf16x8;
typedef __attribute__((ext_vector_type(4))) float f32x4;

__device__ __forceinline__ ushort f2bf(float f) {
  uint32 u = __builtin_bit_cast(uint32, f);
  uint32 r = (u + 0x7fff + ((u >> 16) & 1)) >> 16;  // RNE
  return (ushort)r;
}
__device__ __forceinline__ float bf_lo(uint32 u) {
  return __builtin_bit_cast(float, u << 16);
}
__device__ __forceinline__ float bf_hi(uint32 u) {
  return __builtin_bit_cast(float, u & 0xffff0000u);
}

// ---------------------------------------------------------------------------
// C[M,64] = A[M,K] @ W[64,K]^T via mfma_f32_16x16x32_bf16.  (unchanged)
// ---------------------------------------------------------------------------
template <bool BF16OUT>
__global__ __launch_bounds__(256) void gemm_mfma(const float* __restrict__ A,
                                                 const float* __restrict__ W,
                                                 float* __restrict__ C,
                                                 ushort* __restrict__ Cb,
                                                 int M, int K) {
  __shared__ __align__(16) ushort Ws[64 * 264];
  __shared__ __align__(16) ushort As[128 * 40];
  const int t = threadIdx.x;
  const int lane = t & 63;
  const int w = t >> 6;
  const int quad = lane >> 4;
  const int l16 = lane & 15;
  const int rBase = blockIdx.x * 128;

  const int kq4 = K >> 2;
  for (int idx = t; idx < 64 * kq4; idx += 256) {
    int row = idx / kq4, kq = idx - row * kq4;
    float4 v = *(const float4*)(W + (size_t)row * K + kq * 4);
    ushort4 b;
    b.x = f2bf(v.x); b.y = f2bf(v.y); b.z = f2bf(v.z); b.w = f2bf(v.w);
    *(ushort4*)&Ws[row * 264 + kq * 4] = b;
  }

  f32x4 acc[2][4];
  #pragma unroll
  for (int i = 0; i < 2; ++i)
    #pragma unroll
    for (int n = 0; n < 4; ++n) acc[i][n] = (f32x4){0.f, 0.f, 0.f, 0.f};

  const int rStage = t >> 1;
  const int halfStage = t & 1;

  for (int kb = 0; kb < K; kb += 32) {
    {
      int gr = rBase + rStage;
      #pragma unroll
      for (int q = 0; q < 4; ++q) {
        int kk = kb + halfStage * 16 + q * 4;
        float4 v = make_float4(0.f, 0.f, 0.f, 0.f);
        if (gr < M) v = *(const float4*)(A + (size_t)gr * K + kk);
        ushort4 b;
        b.x = f2bf(v.x); b.y = f2bf(v.y); b.z = f2bf(v.z); b.w = f2bf(v.w);
        *(ushort4*)&As[rStage * 40 + halfStage * 16 + q * 4] = b;
      }
    }
    __syncthreads();

    bf16x8 afrag[2], bfrag[4];
    #pragma unroll
    for (int i = 0; i < 2; ++i)
      afrag[i] = *(const bf16x8*)&As[(w * 32 + i * 16 + l16) * 40 + quad * 8];
    #pragma unroll
    for (int n = 0; n < 4; ++n)
      bfrag[n] = *(const bf16x8*)&Ws[(n * 16 + l16) * 264 + kb + quad * 8];

    #pragma unroll
    for (int i = 0; i < 2; ++i)
      #pragma unroll
      for (int n = 0; n < 4; ++n)
        acc[i][n] = __builtin_amdgcn_mfma_f32_16x16x32_bf16(afrag[i], bfrag[n],
                                                            acc[i][n], 0, 0, 0);
    __syncthreads();
  }

  #pragma unroll
  for (int i = 0; i < 2; ++i)
    #pragma unroll
    for (int nt = 0; nt < 4; ++nt)
      #pragma unroll
      for (int r = 0; r < 4; ++r) {
        int row = rBase + w * 32 + i * 16 + quad * 4 + r;
        int col = nt * 16 + l16;
        if (row < M) {
          if (BF16OUT)
            Cb[(size_t)row * 64 + col] = f2bf(acc[i][nt][r]);
          else
            C[(size_t)row * 64 + col] = acc[i][nt][r];
        }
      }
}

// ---------------------------------------------------------------------------
// Three-level bucket CSR build. All stages run ~780 blocks (full width) AND
// keep long contiguous write runs (>=168 B) so HBM writebacks are full-line:
//   fine bucket  = 128 nodes  (FBITS 7)  -> 782 buckets
//   coarse bucket= 2048 nodes (CBITS 11) -> 49 buckets, 16 fine per coarse
//   stage writes: coarse runs 2048/49 ~= 42 edges; mid runs 2048/16 = 128.
// ---------------------------------------------------------------------------
#define FBITS 7
#define FNODES 128
#define CBITS 11
#define CH 2048
#define S4_CAP 4096
#define P3_CAP 6144

// per-block LDS histogram of fine buckets, flushed via global atomics.
__global__ __launch_bounds__(256) void fine_count(const int* __restrict__ dst,
                                                  int* __restrict__ fineCnt,
                                                  int E, int Bf) {
  __shared__ int lcnt[1024];
  const int t = threadIdx.x;
  for (int i = t; i < Bf; i += 256) lcnt[i] = 0;
  __syncthreads();
  int c0 = blockIdx.x * CH, c1 = min(c0 + CH, E);
  for (int i = c0 + t; i < c1; i += 256) atomicAdd(&lcnt[dst[i] >> FBITS], 1);
  __syncthreads();
  for (int b = t; b < Bf; b += 256) {
    int c = lcnt[b];
    if (c) atomicAdd(&fineCnt[b], c);
  }
}

// single block: exclusive scan of fine counts; derive coarse bases/cursors.
__global__ __launch_bounds__(1024) void scan_fine(const int* __restrict__ fineCnt,
                                                  int* __restrict__ fineBase,
                                                  int* __restrict__ fineCursor,
                                                  int* __restrict__ coarseBase,
                                                  int* __restrict__ coarseCursor,
                                                  int* __restrict__ offsets,
                                                  int Bf, int NC, int N, int E) {
  __shared__ int waveSums[16];
  __shared__ int sExcl[1024];
  const int t = threadIdx.x;
  const int lane = t & 63, wave = t >> 6;
  int x = (t < Bf) ? fineCnt[t] : 0;
  int inc = x;
  #pragma unroll
  for (int d = 1; d < 64; d <<= 1) {
    int o = __shfl_up(inc, d, 64);
    if (lane >= d) inc += o;
  }
  if (lane == 63) waveSums[wave] = inc;
  __syncthreads();
  int wbase = 0;
  #pragma unroll
  for (int w = 0; w < 16; ++w)
    if (w < wave) wbase += waveSums[w];
  int excl = wbase + inc - x;
  sExcl[t] = excl;
  if (t < Bf) {
    fineBase[t] = excl;
    fineCursor[t] = excl;
  }
  if (t == 0) {
    fineBase[Bf] = E;
    offsets[N] = E;
    coarseBase[NC] = E;
  }
  __syncthreads();
  if (t < NC) {
    int v = sExcl[t * 16];
    coarseBase[t] = v;
    coarseCursor[t] = v;
  }
}

// chunk 2048 edges -> 49 coarse buckets; packed = src<<11 | (dst & 2047).
__global__ __launch_bounds__(256) void coarse_partition(const int* __restrict__ src,
                                                        const int* __restrict__ dst,
                                                        int* __restrict__ coarseCursor,
                                                        unsigned* __restrict__ packedA,
                                                        int E, int NC) {
  __shared__ int lcnt[64];
  __shared__ int lbase[64];
  const int t = threadIdx.x;
  if (t < NC) lcnt[t] = 0;
  __syncthreads();
  int c0 = blockIdx.x * CH, c1 = min(c0 + CH, E);
  for (int i = c0 + t; i < c1; i += 256) atomicAdd(&lcnt[dst[i] >> CBITS], 1);
  __syncthreads();
  if (t < NC) {
    int c = lcnt[t];
    lbase[t] = c ? atomicAdd(&coarseCursor[t], c) : 0;
  }
  __syncthreads();
  for (int i = c0 + t; i < c1; i += 256) {
    int dv = dst[i];
    int b = dv >> CBITS;
    int pos = atomicAdd(&lbase[b], 1);
    packedA[pos] = ((unsigned)src[i] << CBITS) | (unsigned)(dv & ((1 << CBITS) - 1));
  }
}

// 16 sub-blocks per coarse region split it into the 16 fine buckets.
// out entries re-packed as src<<7 | (dst & 127).
__global__ __launch_bounds__(256) void mid_partition(const unsigned* __restrict__ packedA,
                                                     const int* __restrict__ coarseBase,
                                                     int* __restrict__ fineCursor,
                                                     unsigned* __restrict__ packedB) {
  __shared__ unsigned stage[S4_CAP];
  __shared__ int cnt[16];
  __shared__ int lbase[16];
  const int cb = blockIdx.x >> 4;
  const int sub = blockIdx.x & 15;
  const int t = threadIdx.x;
  const int base = coarseBase[cb];
  const int endr = coarseBase[cb + 1];
  const int len = endr - base;
  const int chunk = (len + 15) >> 4;
  int s0 = base + sub * chunk;
  int s1 = min(s0 + chunk, endr);
  for (int p0 = s0; p0 < s1; p0 += S4_CAP) {
    const int n = min(S4_CAP, s1 - p0);
    if (t < 16) cnt[t] = 0;
    __syncthreads();
    for (int i = t; i < n; i += 256) {
      unsigned v = packedA[p0 + i];
      stage[i] = v;
      atomicAdd(&cnt[(v >> FBITS) & 15], 1);
    }
    __syncthreads();
    if (t < 16) {
      int c = cnt[t];
      lbase[t] = c ? atomicAdd(&fineCursor[cb * 16 + t], c) : 0;
    }
    __syncthreads();
    for (int i = t; i < n; i += 256) {
      unsigned v = stage[i];
      int f = (v >> FBITS) & 15;
      int pos = atomicAdd(&lbase[f], 1);
      packedB[pos] = ((v >> CBITS) << FBITS) | (v & (FNODES - 1));
    }
    __syncthreads();
  }
}

// one block per fine bucket: LDS stage + per-node rank -> node offsets and
// final dst-sorted edgeSrc (full-line writes, avg run = 64 B).
__global__ __launch_bounds__(256) void fine_finalize(const int* __restrict__ fineBase,
                                                     const unsigned* __restrict__ packedB,
                                                     int* __restrict__ edgeSrc,
                                                     int* __restrict__ offsets, int N) {
  __shared__ unsigned stage[P3_CAP];
  __shared__ int cnt[FNODES];
  const int b = blockIdx.x;
  const int t = threadIdx.x;
  const int base = fineBase[b];
  int n = fineBase[b + 1] - base;
  if (n > P3_CAP) n = P3_CAP;
  for (int i = t; i < n; i += 256) stage[i] = packedB[base + i];
  if (t < FNODES) cnt[t] = 0;
  __syncthreads();
  for (int i = t; i < n; i += 256) atomicAdd(&cnt[stage[i] & (FNODES - 1)], 1);
  __syncthreads();
  if (t < 64) {
    int cA = cnt[2 * t], cB = cnt[2 * t + 1];
    int s = cA + cB;
    int inc = s;
    #pragma unroll
    for (int d = 1; d < 64; d <<= 1) {
      int o = __shfl_up(inc, d, 64);
      if (t >= d) inc += o;
    }
    int excl = inc - s;
    cnt[2 * t] = base + excl;
    cnt[2 * t + 1] = base + excl + cA;
  }
  __syncthreads();
  const int node0 = b << FBITS;
  if (t < FNODES) {
    int g = node0 + t;
    if (g < N) offsets[g] = cnt[t];
  }
  __syncthreads();
  for (int i = t; i < n; i += 256) {
    unsigned v = stage[i];
    int pos = atomicAdd(&cnt[v & (FNODES - 1)], 1);
    edgeSrc[pos] = (int)(v >> FBITS);
  }
}

// ---------------------------------------------------------------------------
// One wave per dst, fused single-gather softmax aggregation.  (unchanged)
// ---------------------------------------------------------------------------
__global__ __launch_bounds__(256) void aggregate(const ushort* __restrict__ zb,
                                                 const float* __restrict__ df,
                                                 const int* __restrict__ offsets,
                                                 const int* __restrict__ edgeSrc,
                                                 float* __restrict__ out, int N) {
  int gwave = (blockIdx.x * blockDim.x + threadIdx.x) >> 6;
  int lane = threadIdx.x & 63;
  if (gwave >= N) return;
  const int d = __builtin_amdgcn_readfirstlane(gwave);
  const int g = lane >> 4;
  const int l16 = lane & 15;
  const int beg = offsets[d];
  const int end = offsets[d + 1];

  const float4 df4 = *(const float4*)(df + (size_t)d * 64 + l16 * 4);

  float m = -INFINITY, l = 0.f;
  float ax = 0.f, ay = 0.f, az = 0.f, aw = 0.f;

  for (int j0 = beg; j0 < end; j0 += 32) {
    const int nst = min(8, (end - j0 + 3) >> 2);
    uint2 zf[8];
    float ew[8];
    float bm = -INFINITY;

    #pragma unroll
    for (int st = 0; st < 8; ++st) {
      if (st < nst) {
        const int eidx = j0 + st * 4 + g;
        const bool act = eidx < end;
        int s = 0;
        if (act) s = edgeSrc[eidx];
        zf[st] = *(const uint2*)(zb + (size_t)s * 64 + l16 * 4);
        float p = bf_lo(zf[st].x) * df4.x;
        p = fmaf(bf_hi(zf[st].x), df4.y, p);
        p = fmaf(bf_lo(zf[st].y), df4.z, p);
        p = fmaf(bf_hi(zf[st].y), df4.w, p);
        p += __shfl_xor(p, 1, 64);
        p += __shfl_xor(p, 2, 64);
        p += __shfl_xor(p, 4, 64);
        p += __shfl_xor(p, 8, 64);
        ew[st] = act ? p : -INFINITY;
        bm = fmaxf(bm, ew[st]);
      }
    }
    bm = fmaxf(bm, __shfl_xor(bm, 16, 64));
    bm = fmaxf(bm, __shfl_xor(bm, 32, 64));

    const float nm = fmaxf(m, bm);
    const float alpha = __expf(m - nm);
    float sw = 0.f;
    #pragma unroll
    for (int st = 0; st < 8; ++st) {
      if (st < nst) {
        const float w = __expf(ew[st] - nm);
        ew[st] = w;
        sw += w;
      }
    }
    sw += __shfl_xor(sw, 16, 64);
    sw += __shfl_xor(sw, 32, 64);
    l = l * alpha + sw;
    m = nm;

    ax *= alpha; ay *= alpha; az *= alpha; aw *= alpha;
    #pragma unroll
    for (int st = 0; st < 8; ++st) {
      if (st < nst) {
        const float w = ew[st];
        ax = fmaf(w, bf_lo(zf[st].x), ax);
        ay = fmaf(w, bf_hi(zf[st].x), ay);
        az = fmaf(w, bf_lo(zf[st].y), az);
        aw = fmaf(w, bf_hi(zf[st].y), aw);
      }
    }
  }

  ax += __shfl_xor(ax, 16, 64); ax += __shfl_xor(ax, 32, 64);
  ay += __shfl_xor(ay, 16, 64); ay += __shfl_xor(ay, 32, 64);
  az += __shfl_xor(az, 16, 64); az += __shfl_xor(az, 32, 64);
  aw += __shfl_xor(aw, 16, 64); aw += __shfl_xor(aw, 32, 64);

  if (lane < 16) {
    const float inv = (l > 0.f) ? (1.f / l) : 0.f;
    float4 o;
    o.x = ax * inv; o.y = ay * inv; o.z = az * inv; o.w = aw * inv;
    *(float4*)(out + (size_t)d * 64 + l16 * 4) = o;
  }
}

// ---------------------------------------------------------------------------
extern "C" void kernel_launch(void* const* d_in, const int* in_sizes, int n_in,
                              void* d_out, int out_size, void* d_ws, size_t ws_size,
                              hipStream_t stream) {
  const float* h     = (const float*)d_in[0];  // [N,256]
  const float* feat  = (const float*)d_in[1];  // [N,64]
  const float* W_fc  = (const float*)d_in[2];  // [64,256]
  const float* W_dst = (const float*)d_in[3];  // [64,64]
  const int*   src   = (const int*)d_in[4];    // [E]
  const int*   dst   = (const int*)d_in[5];    // [E]
  float* out = (float*)d_out;

  const int N = in_sizes[1] / 64;        // 100000
  const int E = in_sizes[4];             // 1600000
  const int IN_DIM = in_sizes[0] / N;    // 256

  const int Bf = (N + FNODES - 1) >> FBITS;   // 782 fine buckets
  const int NC = (Bf + 15) >> 4;              // 49 coarse buckets

  // workspace layout
  char* ws = (char*)d_ws;
  ushort* zb = (ushort*)ws;                        // N*64 bf16
  float* df = (float*)(zb + (size_t)N * 64);       // N*64 f32
  int* offsets = (int*)(df + (size_t)N * 64);      // N+1
  unsigned* packedA = (unsigned*)(offsets + N + 1);// E  (coarse-partitioned, then final edgeSrc)
  int* fineCnt = (int*)(packedA + E);              // Bf
  int* fineBase = fineCnt + Bf;                    // Bf+1
  int* fineCursor = fineBase + Bf + 1;             // Bf
  int* coarseBase = fineCursor + Bf;               // NC+1
  int* coarseCursor = coarseBase + NC + 1;         // NC
  // ping-pong scratch for the mid stage lives in d_out (E u32 <= N*64 f32)
  unsigned* packedB = (unsigned*)d_out;

  hipMemsetAsync(fineCnt, 0, sizeof(int) * (size_t)Bf, stream);

  int ggrid = (N + 127) / 128;  // 782
  gemm_mfma<true><<<ggrid, 256, 0, stream>>>(h, W_fc, nullptr, zb, N, IN_DIM);
  gemm_mfma<false><<<ggrid, 256, 0, stream>>>(feat, W_dst, df, nullptr, N, 64);

  const int pgrid = (E + CH - 1) / CH;  // 782
  fine_count<<<pgrid, 256, 0, stream>>>(dst, fineCnt, E, Bf);
  scan_fine<<<1, 1024, 0, stream>>>(fineCnt, fineBase, fineCursor, coarseBase,
                                    coarseCursor, offsets, Bf, NC, N, E);
  coarse_partition<<<pgrid, 256, 0, stream>>>(src, dst, coarseCursor, packedA, E, NC);
  mid_partition<<<NC * 16, 256, 0, stream>>>(packedA, coarseBase, fineCursor, packedB);
  fine_finalize<<<Bf, 256, 0, stream>>>(fineBase, packedB, (int*)packedA, offsets, N);

  aggregate<<<(N + 3) / 4, 256, 0, stream>>>(zb, df, offsets, (const int*)packedA, out, N);
}

// Round 5
// 358.207 us; speedup vs baseline: 1.3400x; 1.0379x over previous
//
#include <hip/hip_runtime.h>
#include <math.h>

typedef unsigned int uint32;
typedef __attribute__((ext_vector_type(8))) short bf16x8;
typedef __attribute__((ext_vector_type(4))) float f32x4;

__device__ __forceinline__ ushort f2bf(float f) {
  uint32 u = __builtin_bit_cast(uint32, f);
  uint32 r = (u + 0x7fff + ((u >> 16) & 1)) >> 16;  // RNE
  return (ushort)r;
}
__device__ __forceinline__ float bf_lo(uint32 u) {
  return __builtin_bit_cast(float, u << 16);
}
__device__ __forceinline__ float bf_hi(uint32 u) {
  return __builtin_bit_cast(float, u & 0xffff0000u);
}

// ---------------------------------------------------------------------------
// Both projections in ONE launch. Blocks [0,gsplit): h[M,256]@W_fc^T -> zb
// (bf16). Blocks [gsplit,2*gsplit): feat[M,64]@W_dst^T -> df (f32).
// Body identical to the R3-proven gemm_mfma (uniform branch on blockIdx).
// ---------------------------------------------------------------------------
__global__ __launch_bounds__(256) void gemm_both(const float* __restrict__ h,
                                                 const float* __restrict__ feat,
                                                 const float* __restrict__ W_fc,
                                                 const float* __restrict__ W_dst,
                                                 ushort* __restrict__ zb,
                                                 float* __restrict__ df,
                                                 int M, int gsplit) {
  __shared__ __align__(16) ushort Ws[64 * 264];
  __shared__ __align__(16) ushort As[128 * 40];
  const bool second = (int)blockIdx.x >= gsplit;
  const float* __restrict__ A = second ? feat : h;
  const float* __restrict__ W = second ? W_dst : W_fc;
  const int K = second ? 64 : 256;
  const int bx = second ? (int)blockIdx.x - gsplit : (int)blockIdx.x;

  const int t = threadIdx.x;
  const int lane = t & 63;
  const int w = t >> 6;
  const int quad = lane >> 4;
  const int l16 = lane & 15;
  const int rBase = bx * 128;

  const int kq4 = K >> 2;
  for (int idx = t; idx < 64 * kq4; idx += 256) {
    int row = idx / kq4, kq = idx - row * kq4;
    float4 v = *(const float4*)(W + (size_t)row * K + kq * 4);
    ushort4 b;
    b.x = f2bf(v.x); b.y = f2bf(v.y); b.z = f2bf(v.z); b.w = f2bf(v.w);
    *(ushort4*)&Ws[row * 264 + kq * 4] = b;
  }

  f32x4 acc[2][4];
  #pragma unroll
  for (int i = 0; i < 2; ++i)
    #pragma unroll
    for (int n = 0; n < 4; ++n) acc[i][n] = (f32x4){0.f, 0.f, 0.f, 0.f};

  const int rStage = t >> 1;
  const int halfStage = t & 1;

  for (int kb = 0; kb < K; kb += 32) {
    {
      int gr = rBase + rStage;
      #pragma unroll
      for (int q = 0; q < 4; ++q) {
        int kk = kb + halfStage * 16 + q * 4;
        float4 v = make_float4(0.f, 0.f, 0.f, 0.f);
        if (gr < M) v = *(const float4*)(A + (size_t)gr * K + kk);
        ushort4 b;
        b.x = f2bf(v.x); b.y = f2bf(v.y); b.z = f2bf(v.z); b.w = f2bf(v.w);
        *(ushort4*)&As[rStage * 40 + halfStage * 16 + q * 4] = b;
      }
    }
    __syncthreads();

    bf16x8 afrag[2], bfrag[4];
    #pragma unroll
    for (int i = 0; i < 2; ++i)
      afrag[i] = *(const bf16x8*)&As[(w * 32 + i * 16 + l16) * 40 + quad * 8];
    #pragma unroll
    for (int n = 0; n < 4; ++n)
      bfrag[n] = *(const bf16x8*)&Ws[(n * 16 + l16) * 264 + kb + quad * 8];

    #pragma unroll
    for (int i = 0; i < 2; ++i)
      #pragma unroll
      for (int n = 0; n < 4; ++n)
        acc[i][n] = __builtin_amdgcn_mfma_f32_16x16x32_bf16(afrag[i], bfrag[n],
                                                            acc[i][n], 0, 0, 0);
    __syncthreads();
  }

  #pragma unroll
  for (int i = 0; i < 2; ++i)
    #pragma unroll
    for (int nt = 0; nt < 4; ++nt)
      #pragma unroll
      for (int r = 0; r < 4; ++r) {
        int row = rBase + w * 32 + i * 16 + quad * 4 + r;
        int col = nt * 16 + l16;
        if (row < M) {
          if (!second)
            zb[(size_t)row * 64 + col] = f2bf(acc[i][nt][r]);
          else
            df[(size_t)row * 64 + col] = acc[i][nt][r];
        }
      }
}

// ---------------------------------------------------------------------------
// Single-level CSR build: 196 buckets x 512 nodes (NBBITS 9), chunk 4096.
//   count    (391 blocks): per-chunk LDS hist -> global atomicAdd.
//   scan     (1 block)   : exclusive scan of 196 counts -> bBase/bCursor.
//   partition(391 blocks): LDS hist + per-block base reservation + scatter
//                          packed = src<<9 | (dst&511). Runs ~21 edges (84 B).
//   finalize (196 blocks): per-bucket 512-counter hist (global re-read of the
//                          L2-resident packed) -> scan -> node offsets ->
//                          cursor scatter to dst-sorted edgeSrc.
// ---------------------------------------------------------------------------
#define NBBITS 9
#define BKNODES 512
#define CH 4096
#define NBMAX 256

__global__ __launch_bounds__(256) void csr_count(const int* __restrict__ dst,
                                                 int* __restrict__ bCnt, int E, int NB) {
  __shared__ int lcnt[NBMAX];
  const int t = threadIdx.x;
  if (t < NB) lcnt[t] = 0;
  __syncthreads();
  const int c0 = blockIdx.x * CH, c1 = min(c0 + CH, E);
  for (int i = c0 + t; i < c1; i += 256) atomicAdd(&lcnt[dst[i] >> NBBITS], 1);
  __syncthreads();
  if (t < NB) {
    int c = lcnt[t];
    if (c) atomicAdd(&bCnt[t], c);
  }
}

__global__ __launch_bounds__(256) void csr_scan(const int* __restrict__ bCnt,
                                                int* __restrict__ bBase,
                                                int* __restrict__ bCursor,
                                                int* __restrict__ offsets,
                                                int NB, int N, int E) {
  __shared__ int wsum[4];
  const int t = threadIdx.x;
  const int lane = t & 63, wave = t >> 6;
  int x = (t < NB) ? bCnt[t] : 0;
  int inc = x;
  #pragma unroll
  for (int d = 1; d < 64; d <<= 1) {
    int o = __shfl_up(inc, d, 64);
    if (lane >= d) inc += o;
  }
  if (lane == 63) wsum[wave] = inc;
  __syncthreads();
  int wbase = 0;
  #pragma unroll
  for (int w = 0; w < 4; ++w)
    if (w < wave) wbase += wsum[w];
  int excl = wbase + inc - x;
  if (t < NB) {
    bBase[t] = excl;
    bCursor[t] = excl;
  }
  if (t == 0) {
    bBase[NB] = E;
    offsets[N] = E;
  }
}

__global__ __launch_bounds__(256) void csr_partition(const int* __restrict__ src,
                                                     const int* __restrict__ dst,
                                                     int* __restrict__ bCursor,
                                                     unsigned* __restrict__ packed,
                                                     int E, int NB) {
  __shared__ int lcnt[NBMAX];
  __shared__ int lbase[NBMAX];
  const int t = threadIdx.x;
  if (t < NB) lcnt[t] = 0;
  __syncthreads();
  const int c0 = blockIdx.x * CH, c1 = min(c0 + CH, E);
  for (int i = c0 + t; i < c1; i += 256) atomicAdd(&lcnt[dst[i] >> NBBITS], 1);
  __syncthreads();
  if (t < NB) {
    int c = lcnt[t];
    lbase[t] = c ? atomicAdd(&bCursor[t], c) : 0;
  }
  __syncthreads();
  for (int i = c0 + t; i < c1; i += 256) {
    int dv = dst[i];
    int b = dv >> NBBITS;
    int pos = atomicAdd(&lbase[b], 1);
    packed[pos] = ((unsigned)src[i] << NBBITS) | (unsigned)(dv & (BKNODES - 1));
  }
}

__global__ __launch_bounds__(256) void csr_finalize(const int* __restrict__ bBase,
                                                    const unsigned* __restrict__ packed,
                                                    int* __restrict__ edgeSrc,
                                                    int* __restrict__ offsets, int N) {
  __shared__ int sh[BKNODES];
  __shared__ int wsum[4];
  const int r = blockIdx.x;
  const int t = threadIdx.x;
  const int lane = t & 63, wave = t >> 6;
  const int base = bBase[r];
  const int endr = bBase[r + 1];
  for (int i = t; i < BKNODES; i += 256) sh[i] = 0;
  __syncthreads();
  for (int i = base + t; i < endr; i += 256)
    atomicAdd(&sh[packed[i] & (BKNODES - 1)], 1);
  __syncthreads();
  {
    int cA = sh[2 * t], cB = sh[2 * t + 1];
    int s = cA + cB;
    int inc = s;
    #pragma unroll
    for (int d = 1; d < 64; d <<= 1) {
      int o = __shfl_up(inc, d, 64);
      if (lane >= d) inc += o;
    }
    if (lane == 63) wsum[wave] = inc;
    __syncthreads();
    int wbase = 0;
    #pragma unroll
    for (int w = 0; w < 4; ++w)
      if (w < wave) wbase += wsum[w];
    int excl = wbase + inc - s;
    sh[2 * t] = base + excl;
    sh[2 * t + 1] = base + excl + cA;
  }
  __syncthreads();
  const int node0 = r << NBBITS;
  for (int k = t; k < BKNODES; k += 256) {
    int g = node0 + k;
    if (g < N) offsets[g] = sh[k];
  }
  __syncthreads();
  for (int i = base + t; i < endr; i += 256) {
    unsigned v = packed[i];
    int pos = atomicAdd(&sh[v & (BKNODES - 1)], 1);
    edgeSrc[pos] = (int)(v >> NBBITS);
  }
}

// ---------------------------------------------------------------------------
// One wave per dst, fused single-gather softmax aggregation.  (unchanged)
// ---------------------------------------------------------------------------
__global__ __launch_bounds__(256) void aggregate(const ushort* __restrict__ zb,
                                                 const float* __restrict__ df,
                                                 const int* __restrict__ offsets,
                                                 const int* __restrict__ edgeSrc,
                                                 float* __restrict__ out, int N) {
  int gwave = (blockIdx.x * blockDim.x + threadIdx.x) >> 6;
  int lane = threadIdx.x & 63;
  if (gwave >= N) return;
  const int d = __builtin_amdgcn_readfirstlane(gwave);
  const int g = lane >> 4;
  const int l16 = lane & 15;
  const int beg = offsets[d];
  const int end = offsets[d + 1];

  const float4 df4 = *(const float4*)(df + (size_t)d * 64 + l16 * 4);

  float m = -INFINITY, l = 0.f;
  float ax = 0.f, ay = 0.f, az = 0.f, aw = 0.f;

  for (int j0 = beg; j0 < end; j0 += 32) {
    const int nst = min(8, (end - j0 + 3) >> 2);
    uint2 zf[8];
    float ew[8];
    float bm = -INFINITY;

    #pragma unroll
    for (int st = 0; st < 8; ++st) {
      if (st < nst) {
        const int eidx = j0 + st * 4 + g;
        const bool act = eidx < end;
        int s = 0;
        if (act) s = edgeSrc[eidx];
        zf[st] = *(const uint2*)(zb + (size_t)s * 64 + l16 * 4);
        float p = bf_lo(zf[st].x) * df4.x;
        p = fmaf(bf_hi(zf[st].x), df4.y, p);
        p = fmaf(bf_lo(zf[st].y), df4.z, p);
        p = fmaf(bf_hi(zf[st].y), df4.w, p);
        p += __shfl_xor(p, 1, 64);
        p += __shfl_xor(p, 2, 64);
        p += __shfl_xor(p, 4, 64);
        p += __shfl_xor(p, 8, 64);
        ew[st] = act ? p : -INFINITY;
        bm = fmaxf(bm, ew[st]);
      }
    }
    bm = fmaxf(bm, __shfl_xor(bm, 16, 64));
    bm = fmaxf(bm, __shfl_xor(bm, 32, 64));

    const float nm = fmaxf(m, bm);
    const float alpha = __expf(m - nm);
    float sw = 0.f;
    #pragma unroll
    for (int st = 0; st < 8; ++st) {
      if (st < nst) {
        const float w = __expf(ew[st] - nm);
        ew[st] = w;
        sw += w;
      }
    }
    sw += __shfl_xor(sw, 16, 64);
    sw += __shfl_xor(sw, 32, 64);
    l = l * alpha + sw;
    m = nm;

    ax *= alpha; ay *= alpha; az *= alpha; aw *= alpha;
    #pragma unroll
    for (int st = 0; st < 8; ++st) {
      if (st < nst) {
        const float w = ew[st];
        ax = fmaf(w, bf_lo(zf[st].x), ax);
        ay = fmaf(w, bf_hi(zf[st].x), ay);
        az = fmaf(w, bf_lo(zf[st].y), az);
        aw = fmaf(w, bf_hi(zf[st].y), aw);
      }
    }
  }

  ax += __shfl_xor(ax, 16, 64); ax += __shfl_xor(ax, 32, 64);
  ay += __shfl_xor(ay, 16, 64); ay += __shfl_xor(ay, 32, 64);
  az += __shfl_xor(az, 16, 64); az += __shfl_xor(az, 32, 64);
  aw += __shfl_xor(aw, 16, 64); aw += __shfl_xor(aw, 32, 64);

  if (lane < 16) {
    const float inv = (l > 0.f) ? (1.f / l) : 0.f;
    float4 o;
    o.x = ax * inv; o.y = ay * inv; o.z = az * inv; o.w = aw * inv;
    *(float4*)(out + (size_t)d * 64 + l16 * 4) = o;
  }
}

// ---------------------------------------------------------------------------
extern "C" void kernel_launch(void* const* d_in, const int* in_sizes, int n_in,
                              void* d_out, int out_size, void* d_ws, size_t ws_size,
                              hipStream_t stream) {
  const float* h     = (const float*)d_in[0];  // [N,256]
  const float* feat  = (const float*)d_in[1];  // [N,64]
  const float* W_fc  = (const float*)d_in[2];  // [64,256]
  const float* W_dst = (const float*)d_in[3];  // [64,64]
  const int*   src   = (const int*)d_in[4];    // [E]
  const int*   dst   = (const int*)d_in[5];    // [E]
  float* out = (float*)d_out;

  const int N = in_sizes[1] / 64;        // 100000
  const int E = in_sizes[4];             // 1600000

  const int NB = (N + BKNODES - 1) >> NBBITS;  // 196 buckets
  const int nChunks = (E + CH - 1) / CH;       // 391

  // workspace layout
  char* ws = (char*)d_ws;
  ushort* zb = (ushort*)ws;                        // N*64 bf16
  float* df = (float*)(zb + (size_t)N * 64);       // N*64 f32
  int* offsets = (int*)(df + (size_t)N * 64);      // N+1
  int* edgeSrc = offsets + N + 1;                  // E
  int* bCnt = edgeSrc + E;                         // NB
  int* bBase = bCnt + NB;                          // NB+1
  int* bCursor = bBase + NB + 1;                   // NB
  // packed scratch lives in d_out (E u32 <= N*64 f32), consumed before aggregate
  unsigned* packed = (unsigned*)d_out;

  hipMemsetAsync(bCnt, 0, sizeof(int) * (size_t)NB, stream);

  const int gsplit = (N + 127) / 128;  // 782
  gemm_both<<<gsplit * 2, 256, 0, stream>>>(h, feat, W_fc, W_dst, zb, df, N, gsplit);

  csr_count<<<nChunks, 256, 0, stream>>>(dst, bCnt, E, NB);
  csr_scan<<<1, 256, 0, stream>>>(bCnt, bBase, bCursor, offsets, NB, N, E);
  csr_partition<<<nChunks, 256, 0, stream>>>(src, dst, bCursor, packed, E, NB);
  csr_finalize<<<NB, 256, 0, stream>>>(bBase, packed, edgeSrc, offsets, N);

  aggregate<<<(N + 3) / 4, 256, 0, stream>>>(zb, df, offsets, edgeSrc, out, N);
}

// Round 6
// 350.930 us; speedup vs baseline: 1.3678x; 1.0207x over previous
//
#include <hip/hip_runtime.h>
#include <math.h>

typedef unsigned int uint32;
typedef __attribute__((ext_vector_type(8))) short bf16x8;
typedef __attribute__((ext_vector_type(4))) float f32x4;

__device__ __forceinline__ ushort f2bf(float f) {
  uint32 u = __builtin_bit_cast(uint32, f);
  uint32 r = (u + 0x7fff + ((u >> 16) & 1)) >> 16;  // RNE
  return (ushort)r;
}
__device__ __forceinline__ float bf_lo(uint32 u) {
  return __builtin_bit_cast(float, u << 16);
}
__device__ __forceinline__ float bf_hi(uint32 u) {
  return __builtin_bit_cast(float, u & 0xffff0000u);
}

// ---------------------------------------------------------------------------
// Barrier-free-k GEMM: C[M,64] = A[M,K] @ W[64,K]^T, 16x16x32 bf16 MFMA.
// W staged to LDS once (bf16, stride K+8). A fragments loaded DIRECTLY from
// global to registers (wave reads 16 rows x 128 B contiguous per frag pair —
// coalesced at line level), converted to bf16 in-reg. No As LDS, no k-loop
// barriers -> waves free-run, compiler pipelines (unroll 2).
// Rows clamped to M-1 for OOB (MFMA rows independent; stores guarded).
// ---------------------------------------------------------------------------
template <int K, bool BF16OUT>
__device__ __forceinline__ void gemm_body(const float* __restrict__ A,
                                          const float* __restrict__ W,
                                          ushort* __restrict__ Cb,
                                          float* __restrict__ C,
                                          int M, int bx, ushort* Ws) {
  const int t = threadIdx.x;
  const int lane = t & 63;
  const int w = t >> 6;
  const int quad = lane >> 4;
  const int l16 = lane & 15;
  const int rBase = bx * 128;
  const int WSTR = K + 8;

  // stage W[64][K] -> bf16 LDS (coalesced float4 reads), once
  const int kq4 = K >> 2;
  for (int idx = t; idx < 64 * kq4; idx += 256) {
    int row = idx / kq4, kq = idx - row * kq4;
    float4 v = *(const float4*)(W + (size_t)row * K + kq * 4);
    ushort4 b;
    b.x = f2bf(v.x); b.y = f2bf(v.y); b.z = f2bf(v.z); b.w = f2bf(v.w);
    *(ushort4*)&Ws[row * WSTR + kq * 4] = b;
  }
  __syncthreads();

  f32x4 acc[2][4];
  #pragma unroll
  for (int i = 0; i < 2; ++i)
    #pragma unroll
    for (int n = 0; n < 4; ++n) acc[i][n] = (f32x4){0.f, 0.f, 0.f, 0.f};

  // per-lane A row pointers (clamped)
  const int r0 = min(rBase + w * 32 + l16, M - 1);
  const int r1 = min(rBase + w * 32 + 16 + l16, M - 1);
  const float* __restrict__ a0 = A + (size_t)r0 * K + quad * 8;
  const float* __restrict__ a1 = A + (size_t)r1 * K + quad * 8;

  #pragma unroll 2
  for (int kb = 0; kb < K; kb += 32) {
    float4 v00 = *(const float4*)(a0 + kb);
    float4 v01 = *(const float4*)(a0 + kb + 4);
    float4 v10 = *(const float4*)(a1 + kb);
    float4 v11 = *(const float4*)(a1 + kb + 4);
    bf16x8 af0, af1;
    af0[0] = (short)f2bf(v00.x); af0[1] = (short)f2bf(v00.y);
    af0[2] = (short)f2bf(v00.z); af0[3] = (short)f2bf(v00.w);
    af0[4] = (short)f2bf(v01.x); af0[5] = (short)f2bf(v01.y);
    af0[6] = (short)f2bf(v01.z); af0[7] = (short)f2bf(v01.w);
    af1[0] = (short)f2bf(v10.x); af1[1] = (short)f2bf(v10.y);
    af1[2] = (short)f2bf(v10.z); af1[3] = (short)f2bf(v10.w);
    af1[4] = (short)f2bf(v11.x); af1[5] = (short)f2bf(v11.y);
    af1[6] = (short)f2bf(v11.z); af1[7] = (short)f2bf(v11.w);

    bf16x8 bfrag[4];
    #pragma unroll
    for (int n = 0; n < 4; ++n)
      bfrag[n] = *(const bf16x8*)&Ws[(n * 16 + l16) * WSTR + kb + quad * 8];

    #pragma unroll
    for (int n = 0; n < 4; ++n) {
      acc[0][n] = __builtin_amdgcn_mfma_f32_16x16x32_bf16(af0, bfrag[n], acc[0][n], 0, 0, 0);
      acc[1][n] = __builtin_amdgcn_mfma_f32_16x16x32_bf16(af1, bfrag[n], acc[1][n], 0, 0, 0);
    }
  }

  // epilogue: col = nt*16 + l16, row = w*32 + i*16 + quad*4 + r
  #pragma unroll
  for (int i = 0; i < 2; ++i)
    #pragma unroll
    for (int nt = 0; nt < 4; ++nt)
      #pragma unroll
      for (int r = 0; r < 4; ++r) {
        int row = rBase + w * 32 + i * 16 + quad * 4 + r;
        int col = nt * 16 + l16;
        if (row < M) {
          if (BF16OUT)
            Cb[(size_t)row * 64 + col] = f2bf(acc[i][nt][r]);
          else
            C[(size_t)row * 64 + col] = acc[i][nt][r];
        }
      }
}

__global__ __launch_bounds__(256, 4) void gemm_both(const float* __restrict__ h,
                                                    const float* __restrict__ feat,
                                                    const float* __restrict__ W_fc,
                                                    const float* __restrict__ W_dst,
                                                    ushort* __restrict__ zb,
                                                    float* __restrict__ df,
                                                    int M, int gsplit) {
  __shared__ __align__(16) ushort Ws[64 * 264];
  if ((int)blockIdx.x < gsplit)
    gemm_body<256, true>(h, W_fc, zb, nullptr, M, (int)blockIdx.x, Ws);
  else
    gemm_body<64, false>(feat, W_dst, nullptr, df, M, (int)blockIdx.x - gsplit, Ws);
}

// ---------------------------------------------------------------------------
// Single-level CSR build: 196 buckets x 512 nodes (NBBITS 9), chunk 4096.
// (unchanged from R5)
// ---------------------------------------------------------------------------
#define NBBITS 9
#define BKNODES 512
#define CH 4096
#define NBMAX 256

__global__ __launch_bounds__(256) void csr_count(const int* __restrict__ dst,
                                                 int* __restrict__ bCnt, int E, int NB) {
  __shared__ int lcnt[NBMAX];
  const int t = threadIdx.x;
  if (t < NB) lcnt[t] = 0;
  __syncthreads();
  const int c0 = blockIdx.x * CH, c1 = min(c0 + CH, E);
  for (int i = c0 + t; i < c1; i += 256) atomicAdd(&lcnt[dst[i] >> NBBITS], 1);
  __syncthreads();
  if (t < NB) {
    int c = lcnt[t];
    if (c) atomicAdd(&bCnt[t], c);
  }
}

__global__ __launch_bounds__(256) void csr_scan(const int* __restrict__ bCnt,
                                                int* __restrict__ bBase,
                                                int* __restrict__ bCursor,
                                                int* __restrict__ offsets,
                                                int NB, int N, int E) {
  __shared__ int wsum[4];
  const int t = threadIdx.x;
  const int lane = t & 63, wave = t >> 6;
  int x = (t < NB) ? bCnt[t] : 0;
  int inc = x;
  #pragma unroll
  for (int d = 1; d < 64; d <<= 1) {
    int o = __shfl_up(inc, d, 64);
    if (lane >= d) inc += o;
  }
  if (lane == 63) wsum[wave] = inc;
  __syncthreads();
  int wbase = 0;
  #pragma unroll
  for (int w = 0; w < 4; ++w)
    if (w < wave) wbase += wsum[w];
  int excl = wbase + inc - x;
  if (t < NB) {
    bBase[t] = excl;
    bCursor[t] = excl;
  }
  if (t == 0) {
    bBase[NB] = E;
    offsets[N] = E;
  }
}

__global__ __launch_bounds__(256) void csr_partition(const int* __restrict__ src,
                                                     const int* __restrict__ dst,
                                                     int* __restrict__ bCursor,
                                                     unsigned* __restrict__ packed,
                                                     int E, int NB) {
  __shared__ int lcnt[NBMAX];
  __shared__ int lbase[NBMAX];
  const int t = threadIdx.x;
  if (t < NB) lcnt[t] = 0;
  __syncthreads();
  const int c0 = blockIdx.x * CH, c1 = min(c0 + CH, E);
  for (int i = c0 + t; i < c1; i += 256) atomicAdd(&lcnt[dst[i] >> NBBITS], 1);
  __syncthreads();
  if (t < NB) {
    int c = lcnt[t];
    lbase[t] = c ? atomicAdd(&bCursor[t], c) : 0;
  }
  __syncthreads();
  for (int i = c0 + t; i < c1; i += 256) {
    int dv = dst[i];
    int b = dv >> NBBITS;
    int pos = atomicAdd(&lbase[b], 1);
    packed[pos] = ((unsigned)src[i] << NBBITS) | (unsigned)(dv & (BKNODES - 1));
  }
}

__global__ __launch_bounds__(256) void csr_finalize(const int* __restrict__ bBase,
                                                    const unsigned* __restrict__ packed,
                                                    int* __restrict__ edgeSrc,
                                                    int* __restrict__ offsets, int N) {
  __shared__ int sh[BKNODES];
  __shared__ int wsum[4];
  const int r = blockIdx.x;
  const int t = threadIdx.x;
  const int lane = t & 63, wave = t >> 6;
  const int base = bBase[r];
  const int endr = bBase[r + 1];
  for (int i = t; i < BKNODES; i += 256) sh[i] = 0;
  __syncthreads();
  for (int i = base + t; i < endr; i += 256)
    atomicAdd(&sh[packed[i] & (BKNODES - 1)], 1);
  __syncthreads();
  {
    int cA = sh[2 * t], cB = sh[2 * t + 1];
    int s = cA + cB;
    int inc = s;
    #pragma unroll
    for (int d = 1; d < 64; d <<= 1) {
      int o = __shfl_up(inc, d, 64);
      if (lane >= d) inc += o;
    }
    if (lane == 63) wsum[wave] = inc;
    __syncthreads();
    int wbase = 0;
    #pragma unroll
    for (int w = 0; w < 4; ++w)
      if (w < wave) wbase += wsum[w];
    int excl = wbase + inc - s;
    sh[2 * t] = base + excl;
    sh[2 * t + 1] = base + excl + cA;
  }
  __syncthreads();
  const int node0 = r << NBBITS;
  for (int k = t; k < BKNODES; k += 256) {
    int g = node0 + k;
    if (g < N) offsets[g] = sh[k];
  }
  __syncthreads();
  for (int i = base + t; i < endr; i += 256) {
    unsigned v = packed[i];
    int pos = atomicAdd(&sh[v & (BKNODES - 1)], 1);
    edgeSrc[pos] = (int)(v >> NBBITS);
  }
}

// ---------------------------------------------------------------------------
// One wave per dst, fused single-gather softmax aggregation.  (unchanged)
// ---------------------------------------------------------------------------
__global__ __launch_bounds__(256) void aggregate(const ushort* __restrict__ zb,
                                                 const float* __restrict__ df,
                                                 const int* __restrict__ offsets,
                                                 const int* __restrict__ edgeSrc,
                                                 float* __restrict__ out, int N) {
  int gwave = (blockIdx.x * blockDim.x + threadIdx.x) >> 6;
  int lane = threadIdx.x & 63;
  if (gwave >= N) return;
  const int d = __builtin_amdgcn_readfirstlane(gwave);
  const int g = lane >> 4;
  const int l16 = lane & 15;
  const int beg = offsets[d];
  const int end = offsets[d + 1];

  const float4 df4 = *(const float4*)(df + (size_t)d * 64 + l16 * 4);

  float m = -INFINITY, l = 0.f;
  float ax = 0.f, ay = 0.f, az = 0.f, aw = 0.f;

  for (int j0 = beg; j0 < end; j0 += 32) {
    const int nst = min(8, (end - j0 + 3) >> 2);
    uint2 zf[8];
    float ew[8];
    float bm = -INFINITY;

    #pragma unroll
    for (int st = 0; st < 8; ++st) {
      if (st < nst) {
        const int eidx = j0 + st * 4 + g;
        const bool act = eidx < end;
        int s = 0;
        if (act) s = edgeSrc[eidx];
        zf[st] = *(const uint2*)(zb + (size_t)s * 64 + l16 * 4);
        float p = bf_lo(zf[st].x) * df4.x;
        p = fmaf(bf_hi(zf[st].x), df4.y, p);
        p = fmaf(bf_lo(zf[st].y), df4.z, p);
        p = fmaf(bf_hi(zf[st].y), df4.w, p);
        p += __shfl_xor(p, 1, 64);
        p += __shfl_xor(p, 2, 64);
        p += __shfl_xor(p, 4, 64);
        p += __shfl_xor(p, 8, 64);
        ew[st] = act ? p : -INFINITY;
        bm = fmaxf(bm, ew[st]);
      }
    }
    bm = fmaxf(bm, __shfl_xor(bm, 16, 64));
    bm = fmaxf(bm, __shfl_xor(bm, 32, 64));

    const float nm = fmaxf(m, bm);
    const float alpha = __expf(m - nm);
    float sw = 0.f;
    #pragma unroll
    for (int st = 0; st < 8; ++st) {
      if (st < nst) {
        const float w = __expf(ew[st] - nm);
        ew[st] = w;
        sw += w;
      }
    }
    sw += __shfl_xor(sw, 16, 64);
    sw += __shfl_xor(sw, 32, 64);
    l = l * alpha + sw;
    m = nm;

    ax *= alpha; ay *= alpha; az *= alpha; aw *= alpha;
    #pragma unroll
    for (int st = 0; st < 8; ++st) {
      if (st < nst) {
        const float w = ew[st];
        ax = fmaf(w, bf_lo(zf[st].x), ax);
        ay = fmaf(w, bf_hi(zf[st].x), ay);
        az = fmaf(w, bf_lo(zf[st].y), az);
        aw = fmaf(w, bf_hi(zf[st].y), aw);
      }
    }
  }

  ax += __shfl_xor(ax, 16, 64); ax += __shfl_xor(ax, 32, 64);
  ay += __shfl_xor(ay, 16, 64); ay += __shfl_xor(ay, 32, 64);
  az += __shfl_xor(az, 16, 64); az += __shfl_xor(az, 32, 64);
  aw += __shfl_xor(aw, 16, 64); aw += __shfl_xor(aw, 32, 64);

  if (lane < 16) {
    const float inv = (l > 0.f) ? (1.f / l) : 0.f;
    float4 o;
    o.x = ax * inv; o.y = ay * inv; o.z = az * inv; o.w = aw * inv;
    *(float4*)(out + (size_t)d * 64 + l16 * 4) = o;
  }
}

// ---------------------------------------------------------------------------
extern "C" void kernel_launch(void* const* d_in, const int* in_sizes, int n_in,
                              void* d_out, int out_size, void* d_ws, size_t ws_size,
                              hipStream_t stream) {
  const float* h     = (const float*)d_in[0];  // [N,256]
  const float* feat  = (const float*)d_in[1];  // [N,64]
  const float* W_fc  = (const float*)d_in[2];  // [64,256]
  const float* W_dst = (const float*)d_in[3];  // [64,64]
  const int*   src   = (const int*)d_in[4];    // [E]
  const int*   dst   = (const int*)d_in[5];    // [E]
  float* out = (float*)d_out;

  const int N = in_sizes[1] / 64;        // 100000
  const int E = in_sizes[4];             // 1600000

  const int NB = (N + BKNODES - 1) >> NBBITS;  // 196 buckets
  const int nChunks = (E + CH - 1) / CH;       // 391

  // workspace layout
  char* ws = (char*)d_ws;
  ushort* zb = (ushort*)ws;                        // N*64 bf16
  float* df = (float*)(zb + (size_t)N * 64);       // N*64 f32
  int* offsets = (int*)(df + (size_t)N * 64);      // N+1
  int* edgeSrc = offsets + N + 1;                  // E
  int* bCnt = edgeSrc + E;                         // NB
  int* bBase = bCnt + NB;                          // NB+1
  int* bCursor = bBase + NB + 1;                   // NB
  // packed scratch lives in d_out (E u32 <= N*64 f32), consumed before aggregate
  unsigned* packed = (unsigned*)d_out;

  hipMemsetAsync(bCnt, 0, sizeof(int) * (size_t)NB, stream);

  const int gsplit = (N + 127) / 128;  // 782
  gemm_both<<<gsplit * 2, 256, 0, stream>>>(h, feat, W_fc, W_dst, zb, df, N, gsplit);

  csr_count<<<nChunks, 256, 0, stream>>>(dst, bCnt, E, NB);
  csr_scan<<<1, 256, 0, stream>>>(bCnt, bBase, bCursor, offsets, NB, N, E);
  csr_partition<<<nChunks, 256, 0, stream>>>(src, dst, bCursor, packed, E, NB);
  csr_finalize<<<NB, 256, 0, stream>>>(bBase, packed, edgeSrc, offsets, N);

  aggregate<<<(N + 3) / 4, 256, 0, stream>>>(zb, df, offsets, edgeSrc, out, N);
}

// Round 7
// 335.198 us; speedup vs baseline: 1.4320x; 1.0469x over previous
//
#include <hip/hip_runtime.h>
#include <math.h>

typedef unsigned int uint32;
typedef __attribute__((ext_vector_type(8))) short bf16x8;
typedef __attribute__((ext_vector_type(4))) float f32x4;

__device__ __forceinline__ ushort f2bf(float f) {
  uint32 u = __builtin_bit_cast(uint32, f);
  uint32 r = (u + 0x7fff + ((u >> 16) & 1)) >> 16;  // RNE
  return (ushort)r;
}
__device__ __forceinline__ float bf_lo(uint32 u) {
  return __builtin_bit_cast(float, u << 16);
}
__device__ __forceinline__ float bf_hi(uint32 u) {
  return __builtin_bit_cast(float, u & 0xffff0000u);
}

// ---------------------------------------------------------------------------
// Barrier-free-k GEMM (unchanged from R6, measured ~70 us).
// ---------------------------------------------------------------------------
template <int K, bool BF16OUT>
__device__ __forceinline__ void gemm_body(const float* __restrict__ A,
                                          const float* __restrict__ W,
                                          ushort* __restrict__ Cb,
                                          float* __restrict__ C,
                                          int M, int bx, ushort* Ws) {
  const int t = threadIdx.x;
  const int lane = t & 63;
  const int w = t >> 6;
  const int quad = lane >> 4;
  const int l16 = lane & 15;
  const int rBase = bx * 128;
  const int WSTR = K + 8;

  const int kq4 = K >> 2;
  for (int idx = t; idx < 64 * kq4; idx += 256) {
    int row = idx / kq4, kq = idx - row * kq4;
    float4 v = *(const float4*)(W + (size_t)row * K + kq * 4);
    ushort4 b;
    b.x = f2bf(v.x); b.y = f2bf(v.y); b.z = f2bf(v.z); b.w = f2bf(v.w);
    *(ushort4*)&Ws[row * WSTR + kq * 4] = b;
  }
  __syncthreads();

  f32x4 acc[2][4];
  #pragma unroll
  for (int i = 0; i < 2; ++i)
    #pragma unroll
    for (int n = 0; n < 4; ++n) acc[i][n] = (f32x4){0.f, 0.f, 0.f, 0.f};

  const int r0 = min(rBase + w * 32 + l16, M - 1);
  const int r1 = min(rBase + w * 32 + 16 + l16, M - 1);
  const float* __restrict__ a0 = A + (size_t)r0 * K + quad * 8;
  const float* __restrict__ a1 = A + (size_t)r1 * K + quad * 8;

  #pragma unroll 2
  for (int kb = 0; kb < K; kb += 32) {
    float4 v00 = *(const float4*)(a0 + kb);
    float4 v01 = *(const float4*)(a0 + kb + 4);
    float4 v10 = *(const float4*)(a1 + kb);
    float4 v11 = *(const float4*)(a1 + kb + 4);
    bf16x8 af0, af1;
    af0[0] = (short)f2bf(v00.x); af0[1] = (short)f2bf(v00.y);
    af0[2] = (short)f2bf(v00.z); af0[3] = (short)f2bf(v00.w);
    af0[4] = (short)f2bf(v01.x); af0[5] = (short)f2bf(v01.y);
    af0[6] = (short)f2bf(v01.z); af0[7] = (short)f2bf(v01.w);
    af1[0] = (short)f2bf(v10.x); af1[1] = (short)f2bf(v10.y);
    af1[2] = (short)f2bf(v10.z); af1[3] = (short)f2bf(v10.w);
    af1[4] = (short)f2bf(v11.x); af1[5] = (short)f2bf(v11.y);
    af1[6] = (short)f2bf(v11.z); af1[7] = (short)f2bf(v11.w);

    bf16x8 bfrag[4];
    #pragma unroll
    for (int n = 0; n < 4; ++n)
      bfrag[n] = *(const bf16x8*)&Ws[(n * 16 + l16) * WSTR + kb + quad * 8];

    #pragma unroll
    for (int n = 0; n < 4; ++n) {
      acc[0][n] = __builtin_amdgcn_mfma_f32_16x16x32_bf16(af0, bfrag[n], acc[0][n], 0, 0, 0);
      acc[1][n] = __builtin_amdgcn_mfma_f32_16x16x32_bf16(af1, bfrag[n], acc[1][n], 0, 0, 0);
    }
  }

  #pragma unroll
  for (int i = 0; i < 2; ++i)
    #pragma unroll
    for (int nt = 0; nt < 4; ++nt)
      #pragma unroll
      for (int r = 0; r < 4; ++r) {
        int row = rBase + w * 32 + i * 16 + quad * 4 + r;
        int col = nt * 16 + l16;
        if (row < M) {
          if (BF16OUT)
            Cb[(size_t)row * 64 + col] = f2bf(acc[i][nt][r]);
          else
            C[(size_t)row * 64 + col] = acc[i][nt][r];
        }
      }
}

__global__ __launch_bounds__(256, 4) void gemm_both(const float* __restrict__ h,
                                                    const float* __restrict__ feat,
                                                    const float* __restrict__ W_fc,
                                                    const float* __restrict__ W_dst,
                                                    ushort* __restrict__ zb,
                                                    float* __restrict__ df,
                                                    int M, int gsplit) {
  __shared__ __align__(16) ushort Ws[64 * 264];
  if ((int)blockIdx.x < gsplit)
    gemm_body<256, true>(h, W_fc, zb, nullptr, M, (int)blockIdx.x, Ws);
  else
    gemm_body<64, false>(feat, W_dst, nullptr, df, M, (int)blockIdx.x - gsplit, Ws);
}

// ---------------------------------------------------------------------------
// Single-level CSR build: 391 buckets x 256 nodes (NBBITS 8), chunk 4096.
//   count/partition: 391 blocks each (strided LDS hist loops, NB>256).
//   scan: 512 threads.
//   finalize: 391 blocks (2x the width of R6's 196), one counter per thread.
// ---------------------------------------------------------------------------
#define NBBITS 8
#define BKNODES 256
#define CH 4096
#define NBMAX 512

__global__ __launch_bounds__(256) void csr_count(const int* __restrict__ dst,
                                                 int* __restrict__ bCnt, int E, int NB) {
  __shared__ int lcnt[NBMAX];
  const int t = threadIdx.x;
  for (int i = t; i < NB; i += 256) lcnt[i] = 0;
  __syncthreads();
  const int c0 = blockIdx.x * CH, c1 = min(c0 + CH, E);
  for (int i = c0 + t; i < c1; i += 256) atomicAdd(&lcnt[dst[i] >> NBBITS], 1);
  __syncthreads();
  for (int b = t; b < NB; b += 256) {
    int c = lcnt[b];
    if (c) atomicAdd(&bCnt[b], c);
  }
}

__global__ __launch_bounds__(512) void csr_scan(const int* __restrict__ bCnt,
                                                int* __restrict__ bBase,
                                                int* __restrict__ bCursor,
                                                int* __restrict__ offsets,
                                                int NB, int N, int E) {
  __shared__ int wsum[8];
  const int t = threadIdx.x;
  const int lane = t & 63, wave = t >> 6;
  int x = (t < NB) ? bCnt[t] : 0;
  int inc = x;
  #pragma unroll
  for (int d = 1; d < 64; d <<= 1) {
    int o = __shfl_up(inc, d, 64);
    if (lane >= d) inc += o;
  }
  if (lane == 63) wsum[wave] = inc;
  __syncthreads();
  int wbase = 0;
  #pragma unroll
  for (int w = 0; w < 8; ++w)
    if (w < wave) wbase += wsum[w];
  int excl = wbase + inc - x;
  if (t < NB) {
    bBase[t] = excl;
    bCursor[t] = excl;
  }
  if (t == 0) {
    bBase[NB] = E;
    offsets[N] = E;
  }
}

__global__ __launch_bounds__(256) void csr_partition(const int* __restrict__ src,
                                                     const int* __restrict__ dst,
                                                     int* __restrict__ bCursor,
                                                     unsigned* __restrict__ packed,
                                                     int E, int NB) {
  __shared__ int lcnt[NBMAX];
  __shared__ int lbase[NBMAX];
  const int t = threadIdx.x;
  for (int i = t; i < NB; i += 256) lcnt[i] = 0;
  __syncthreads();
  const int c0 = blockIdx.x * CH, c1 = min(c0 + CH, E);
  for (int i = c0 + t; i < c1; i += 256) atomicAdd(&lcnt[dst[i] >> NBBITS], 1);
  __syncthreads();
  for (int b = t; b < NB; b += 256) {
    int c = lcnt[b];
    lbase[b] = c ? atomicAdd(&bCursor[b], c) : 0;
  }
  __syncthreads();
  for (int i = c0 + t; i < c1; i += 256) {
    int dv = dst[i];
    int b = dv >> NBBITS;
    int pos = atomicAdd(&lbase[b], 1);
    packed[pos] = ((unsigned)src[i] << NBBITS) | (unsigned)(dv & (BKNODES - 1));
  }
}

__global__ __launch_bounds__(256) void csr_finalize(const int* __restrict__ bBase,
                                                    const unsigned* __restrict__ packed,
                                                    int* __restrict__ edgeSrc,
                                                    int* __restrict__ offsets, int N) {
  __shared__ int sh[BKNODES];
  __shared__ int wsum[4];
  const int r = blockIdx.x;
  const int t = threadIdx.x;
  const int lane = t & 63, wave = t >> 6;
  const int base = bBase[r];
  const int endr = bBase[r + 1];
  sh[t] = 0;
  __syncthreads();
  for (int i = base + t; i < endr; i += 256)
    atomicAdd(&sh[packed[i] & (BKNODES - 1)], 1);
  __syncthreads();
  {
    int x = sh[t];
    int inc = x;
    #pragma unroll
    for (int d = 1; d < 64; d <<= 1) {
      int o = __shfl_up(inc, d, 64);
      if (lane >= d) inc += o;
    }
    if (lane == 63) wsum[wave] = inc;
    __syncthreads();
    int wbase = 0;
    #pragma unroll
    for (int w = 0; w < 4; ++w)
      if (w < wave) wbase += wsum[w];
    int excl = wbase + inc - x;
    __syncthreads();
    sh[t] = base + excl;
  }
  __syncthreads();
  const int node0 = r << NBBITS;
  {
    int g = node0 + t;
    if (g < N) offsets[g] = sh[t];
  }
  __syncthreads();
  for (int i = base + t; i < endr; i += 256) {
    unsigned v = packed[i];
    int pos = atomicAdd(&sh[v & (BKNODES - 1)], 1);
    edgeSrc[pos] = (int)(v >> NBBITS);
  }
}

// ---------------------------------------------------------------------------
// Grid-stride persistent-wave aggregate: 8192 waves, each handles ~12 dsts.
// Per-dst header (beg/end/df4) for the NEXT dst is prefetched before
// processing the current one (hides the serial prologue latency that
// dominated the one-wave-per-dst version). Inner edge loop unchanged.
// ---------------------------------------------------------------------------
__global__ __launch_bounds__(256) void aggregate(const ushort* __restrict__ zb,
                                                 const float* __restrict__ df,
                                                 const int* __restrict__ offsets,
                                                 const int* __restrict__ edgeSrc,
                                                 float* __restrict__ out, int N, int NW) {
  const int lane = threadIdx.x & 63;
  int d = __builtin_amdgcn_readfirstlane((int)((blockIdx.x * blockDim.x + threadIdx.x) >> 6));
  if (d >= N) return;
  const int g = lane >> 4;
  const int l16 = lane & 15;

  int beg = offsets[d];
  int end = offsets[d + 1];
  float4 df4 = *(const float4*)(df + (size_t)d * 64 + l16 * 4);

  while (true) {
    // prefetch next dst's header (clamped; wave-uniform)
    const int nd = d + NW;
    const int ndc = min(nd, N - 1);
    const int nbeg = offsets[ndc];
    const int nend = offsets[ndc + 1];
    const float4 ndf4 = *(const float4*)(df + (size_t)ndc * 64 + l16 * 4);

    float m = -INFINITY, l = 0.f;
    float ax = 0.f, ay = 0.f, az = 0.f, aw = 0.f;

    for (int j0 = beg; j0 < end; j0 += 32) {
      const int nst = min(8, (end - j0 + 3) >> 2);
      uint2 zf[8];
      float ew[8];
      float bm = -INFINITY;

      #pragma unroll
      for (int st = 0; st < 8; ++st) {
        if (st < nst) {
          const int eidx = j0 + st * 4 + g;
          const bool act = eidx < end;
          int s = 0;
          if (act) s = edgeSrc[eidx];
          zf[st] = *(const uint2*)(zb + (size_t)s * 64 + l16 * 4);
          float p = bf_lo(zf[st].x) * df4.x;
          p = fmaf(bf_hi(zf[st].x), df4.y, p);
          p = fmaf(bf_lo(zf[st].y), df4.z, p);
          p = fmaf(bf_hi(zf[st].y), df4.w, p);
          p += __shfl_xor(p, 1, 64);
          p += __shfl_xor(p, 2, 64);
          p += __shfl_xor(p, 4, 64);
          p += __shfl_xor(p, 8, 64);
          ew[st] = act ? p : -INFINITY;
          bm = fmaxf(bm, ew[st]);
        }
      }
      bm = fmaxf(bm, __shfl_xor(bm, 16, 64));
      bm = fmaxf(bm, __shfl_xor(bm, 32, 64));

      const float nm = fmaxf(m, bm);
      const float alpha = __expf(m - nm);
      float sw = 0.f;
      #pragma unroll
      for (int st = 0; st < 8; ++st) {
        if (st < nst) {
          const float w = __expf(ew[st] - nm);
          ew[st] = w;
          sw += w;
        }
      }
      sw += __shfl_xor(sw, 16, 64);
      sw += __shfl_xor(sw, 32, 64);
      l = l * alpha + sw;
      m = nm;

      ax *= alpha; ay *= alpha; az *= alpha; aw *= alpha;
      #pragma unroll
      for (int st = 0; st < 8; ++st) {
        if (st < nst) {
          const float w = ew[st];
          ax = fmaf(w, bf_lo(zf[st].x), ax);
          ay = fmaf(w, bf_hi(zf[st].x), ay);
          az = fmaf(w, bf_lo(zf[st].y), az);
          aw = fmaf(w, bf_hi(zf[st].y), aw);
        }
      }
    }

    ax += __shfl_xor(ax, 16, 64); ax += __shfl_xor(ax, 32, 64);
    ay += __shfl_xor(ay, 16, 64); ay += __shfl_xor(ay, 32, 64);
    az += __shfl_xor(az, 16, 64); az += __shfl_xor(az, 32, 64);
    aw += __shfl_xor(aw, 16, 64); aw += __shfl_xor(aw, 32, 64);

    if (lane < 16) {
      const float inv = (l > 0.f) ? (1.f / l) : 0.f;
      float4 o;
      o.x = ax * inv; o.y = ay * inv; o.z = az * inv; o.w = aw * inv;
      *(float4*)(out + (size_t)d * 64 + l16 * 4) = o;
    }

    if (nd >= N) break;
    d = nd; beg = nbeg; end = nend; df4 = ndf4;
  }
}

// ---------------------------------------------------------------------------
extern "C" void kernel_launch(void* const* d_in, const int* in_sizes, int n_in,
                              void* d_out, int out_size, void* d_ws, size_t ws_size,
                              hipStream_t stream) {
  const float* h     = (const float*)d_in[0];  // [N,256]
  const float* feat  = (const float*)d_in[1];  // [N,64]
  const float* W_fc  = (const float*)d_in[2];  // [64,256]
  const float* W_dst = (const float*)d_in[3];  // [64,64]
  const int*   src   = (const int*)d_in[4];    // [E]
  const int*   dst   = (const int*)d_in[5];    // [E]
  float* out = (float*)d_out;

  const int N = in_sizes[1] / 64;        // 100000
  const int E = in_sizes[4];             // 1600000

  const int NB = (N + BKNODES - 1) >> NBBITS;  // 391 buckets
  const int nChunks = (E + CH - 1) / CH;       // 391

  // workspace layout
  char* ws = (char*)d_ws;
  ushort* zb = (ushort*)ws;                        // N*64 bf16
  float* df = (float*)(zb + (size_t)N * 64);       // N*64 f32
  int* offsets = (int*)(df + (size_t)N * 64);      // N+1
  int* edgeSrc = offsets + N + 1;                  // E
  int* bCnt = edgeSrc + E;                         // NB
  int* bBase = bCnt + NB;                          // NB+1
  int* bCursor = bBase + NB + 1;                   // NB
  // packed scratch lives in d_out (E u32 <= N*64 f32), consumed before aggregate
  unsigned* packed = (unsigned*)d_out;

  hipMemsetAsync(bCnt, 0, sizeof(int) * (size_t)NB, stream);

  const int gsplit = (N + 127) / 128;  // 782
  gemm_both<<<gsplit * 2, 256, 0, stream>>>(h, feat, W_fc, W_dst, zb, df, N, gsplit);

  csr_count<<<nChunks, 256, 0, stream>>>(dst, bCnt, E, NB);
  csr_scan<<<1, 512, 0, stream>>>(bCnt, bBase, bCursor, offsets, NB, N, E);
  csr_partition<<<nChunks, 256, 0, stream>>>(src, dst, bCursor, packed, E, NB);
  csr_finalize<<<NB, 256, 0, stream>>>(bBase, packed, edgeSrc, offsets, N);

  // persistent-wave aggregate: 2048 blocks x 4 waves = 8192 waves
  const int aggBlocks = 2048;
  const int NW = aggBlocks * 4;
  aggregate<<<aggBlocks, 256, 0, stream>>>(zb, df, offsets, edgeSrc, out, N, NW);
}

// Round 8
// 328.743 us; speedup vs baseline: 1.4601x; 1.0196x over previous
//
#include <hip/hip_runtime.h>
#include <math.h>

typedef unsigned int uint32;
typedef __attribute__((ext_vector_type(8))) short bf16x8;
typedef __attribute__((ext_vector_type(4))) float f32x4;

__device__ __forceinline__ ushort f2bf(float f) {
  uint32 u = __builtin_bit_cast(uint32, f);
  uint32 r = (u + 0x7fff + ((u >> 16) & 1)) >> 16;  // RNE
  return (ushort)r;
}
__device__ __forceinline__ float bf_lo(uint32 u) {
  return __builtin_bit_cast(float, u << 16);
}
__device__ __forceinline__ float bf_hi(uint32 u) {
  return __builtin_bit_cast(float, u & 0xffff0000u);
}

#define NBBITS 8
#define BKNODES 256
#define CH 4096
#define NBMAX 512

// ---------------------------------------------------------------------------
// GEMM body with depth-1 register prefetch: loads for iter kb+32 are issued
// BEFORE the convert+MFMA of iter kb (R6 lesson: barrier-free alone doesn't
// hide HBM latency; prefetch depth does).
// ---------------------------------------------------------------------------
template <int K, bool BF16OUT>
__device__ __forceinline__ void gemm_body(const float* __restrict__ A,
                                          const float* __restrict__ W,
                                          ushort* __restrict__ Cb,
                                          float* __restrict__ C,
                                          int M, int bx, ushort* Ws) {
  const int t = threadIdx.x;
  const int lane = t & 63;
  const int w = t >> 6;
  const int quad = lane >> 4;
  const int l16 = lane & 15;
  const int rBase = bx * 128;
  const int WSTR = K + 8;

  const int kq4 = K >> 2;
  for (int idx = t; idx < 64 * kq4; idx += 256) {
    int row = idx / kq4, kq = idx - row * kq4;
    float4 v = *(const float4*)(W + (size_t)row * K + kq * 4);
    ushort4 b;
    b.x = f2bf(v.x); b.y = f2bf(v.y); b.z = f2bf(v.z); b.w = f2bf(v.w);
    *(ushort4*)&Ws[row * WSTR + kq * 4] = b;
  }
  __syncthreads();

  f32x4 acc[2][4];
  #pragma unroll
  for (int i = 0; i < 2; ++i)
    #pragma unroll
    for (int n = 0; n < 4; ++n) acc[i][n] = (f32x4){0.f, 0.f, 0.f, 0.f};

  const int r0 = min(rBase + w * 32 + l16, M - 1);
  const int r1 = min(rBase + w * 32 + 16 + l16, M - 1);
  const float* __restrict__ a0 = A + (size_t)r0 * K + quad * 8;
  const float* __restrict__ a1 = A + (size_t)r1 * K + quad * 8;

  float4 c00 = *(const float4*)(a0);
  float4 c01 = *(const float4*)(a0 + 4);
  float4 c10 = *(const float4*)(a1);
  float4 c11 = *(const float4*)(a1 + 4);

  #pragma unroll 2
  for (int kb = 0; kb < K; kb += 32) {
    float4 n00, n01, n10, n11;
    const bool more = (kb + 32 < K);
    if (more) {
      n00 = *(const float4*)(a0 + kb + 32);
      n01 = *(const float4*)(a0 + kb + 36);
      n10 = *(const float4*)(a1 + kb + 32);
      n11 = *(const float4*)(a1 + kb + 36);
    }

    bf16x8 af0, af1;
    af0[0] = (short)f2bf(c00.x); af0[1] = (short)f2bf(c00.y);
    af0[2] = (short)f2bf(c00.z); af0[3] = (short)f2bf(c00.w);
    af0[4] = (short)f2bf(c01.x); af0[5] = (short)f2bf(c01.y);
    af0[6] = (short)f2bf(c01.z); af0[7] = (short)f2bf(c01.w);
    af1[0] = (short)f2bf(c10.x); af1[1] = (short)f2bf(c10.y);
    af1[2] = (short)f2bf(c10.z); af1[3] = (short)f2bf(c10.w);
    af1[4] = (short)f2bf(c11.x); af1[5] = (short)f2bf(c11.y);
    af1[6] = (short)f2bf(c11.z); af1[7] = (short)f2bf(c11.w);

    bf16x8 bfrag[4];
    #pragma unroll
    for (int n = 0; n < 4; ++n)
      bfrag[n] = *(const bf16x8*)&Ws[(n * 16 + l16) * WSTR + kb + quad * 8];

    #pragma unroll
    for (int n = 0; n < 4; ++n) {
      acc[0][n] = __builtin_amdgcn_mfma_f32_16x16x32_bf16(af0, bfrag[n], acc[0][n], 0, 0, 0);
      acc[1][n] = __builtin_amdgcn_mfma_f32_16x16x32_bf16(af1, bfrag[n], acc[1][n], 0, 0, 0);
    }

    if (more) { c00 = n00; c01 = n01; c10 = n10; c11 = n11; }
  }

  #pragma unroll
  for (int i = 0; i < 2; ++i)
    #pragma unroll
    for (int nt = 0; nt < 4; ++nt)
      #pragma unroll
      for (int r = 0; r < 4; ++r) {
        int row = rBase + w * 32 + i * 16 + quad * 4 + r;
        int col = nt * 16 + l16;
        if (row < M) {
          if (BF16OUT)
            Cb[(size_t)row * 64 + col] = f2bf(acc[i][nt][r]);
          else
            C[(size_t)row * 64 + col] = acc[i][nt][r];
        }
      }
}

// count path (uses the gemm kernel's LDS reinterpreted as int histogram)
__device__ __forceinline__ void count_body(const int* __restrict__ dst,
                                           int* __restrict__ bCnt,
                                           int E, int NB, int cb, int* lcnt) {
  const int t = threadIdx.x;
  for (int i = t; i < NB; i += 256) lcnt[i] = 0;
  __syncthreads();
  const int c0 = cb * CH, c1 = min(c0 + CH, E);
  for (int i = c0 + t; i < c1; i += 256) atomicAdd(&lcnt[dst[i] >> NBBITS], 1);
  __syncthreads();
  for (int b = t; b < NB; b += 256) {
    int c = lcnt[b];
    if (c) atomicAdd(&bCnt[b], c);
  }
}

// Fused: blocks [0,nChunks) do csr_count (start first -> overlap with gemm);
// blocks [nChunks, nChunks+gsplit) do the 256-K gemm; rest do the 64-K gemm.
__global__ __launch_bounds__(256, 4) void gemm_count(const float* __restrict__ h,
                                                     const float* __restrict__ feat,
                                                     const float* __restrict__ W_fc,
                                                     const float* __restrict__ W_dst,
                                                     ushort* __restrict__ zb,
                                                     float* __restrict__ df,
                                                     const int* __restrict__ dst,
                                                     int* __restrict__ bCnt,
                                                     int M, int gsplit, int E, int NB,
                                                     int nChunks) {
  __shared__ __align__(16) ushort Ws[64 * 264];
  const int bx = (int)blockIdx.x;
  if (bx < nChunks)
    count_body(dst, bCnt, E, NB, bx, (int*)Ws);
  else if (bx < nChunks + gsplit)
    gemm_body<256, true>(h, W_fc, zb, nullptr, M, bx - nChunks, Ws);
  else
    gemm_body<64, false>(feat, W_dst, nullptr, df, M, bx - nChunks - gsplit, Ws);
}

// ---------------------------------------------------------------------------
// Self-scan helper: inclusive Hillis-Steele over NBMAX(512) counts in LDS.
// Each block recomputes the (cheap) scan; removes the csr_scan dispatch.
// ---------------------------------------------------------------------------
__device__ __forceinline__ void block_scan512(const int* __restrict__ bCnt,
                                              int NB, int* sc) {
  const int t = threadIdx.x;
  {
    int v0 = (t < NB) ? bCnt[t] : 0;
    int v1 = (t + 256 < NB) ? bCnt[t + 256] : 0;
    sc[t] = v0;
    sc[t + 256] = v1;
  }
  __syncthreads();
  for (int off = 1; off < NBMAX; off <<= 1) {
    int v0 = sc[t];
    int a0 = (t >= off) ? sc[t - off] : 0;
    int v1 = sc[t + 256];
    int a1 = sc[t + 256 - off];
    __syncthreads();
    sc[t] = v0 + a0;
    sc[t + 256] = v1 + a1;
    __syncthreads();
  }
}

__global__ __launch_bounds__(256) void csr_partition(const int* __restrict__ src,
                                                     const int* __restrict__ dst,
                                                     const int* __restrict__ bCnt,
                                                     int* __restrict__ relCur,
                                                     unsigned* __restrict__ packed,
                                                     int E, int NB) {
  __shared__ int sc[NBMAX];
  __shared__ int lcnt[NBMAX];
  __shared__ int lbase[NBMAX];
  const int t = threadIdx.x;
  block_scan512(bCnt, NB, sc);  // sc = inclusive scan
  for (int i = t; i < NB; i += 256) lcnt[i] = 0;
  __syncthreads();
  const int c0 = blockIdx.x * CH, c1 = min(c0 + CH, E);
  for (int i = c0 + t; i < c1; i += 256) atomicAdd(&lcnt[dst[i] >> NBBITS], 1);
  __syncthreads();
  for (int b = t; b < NB; b += 256) {
    int c = lcnt[b];
    lbase[b] = c ? (sc[b] - bCnt[b] + atomicAdd(&relCur[b], c)) : 0;
  }
  __syncthreads();
  for (int i = c0 + t; i < c1; i += 256) {
    int dv = dst[i];
    int b = dv >> NBBITS;
    int pos = atomicAdd(&lbase[b], 1);
    packed[pos] = ((unsigned)src[i] << NBBITS) | (unsigned)(dv & (BKNODES - 1));
  }
}

__global__ __launch_bounds__(256) void csr_finalize(const int* __restrict__ bCnt,
                                                    const unsigned* __restrict__ packed,
                                                    int* __restrict__ edgeSrc,
                                                    int* __restrict__ offsets,
                                                    int N, int NB, int E) {
  __shared__ int sc[NBMAX];
  __shared__ int sh[BKNODES];
  __shared__ int wsum[4];
  const int r = blockIdx.x;
  const int t = threadIdx.x;
  const int lane = t & 63, wave = t >> 6;
  block_scan512(bCnt, NB, sc);
  const int endr = sc[r];
  const int base = endr - bCnt[r];
  __syncthreads();
  sh[t] = 0;
  __syncthreads();
  for (int i = base + t; i < endr; i += 256)
    atomicAdd(&sh[packed[i] & (BKNODES - 1)], 1);
  __syncthreads();
  {
    int x = sh[t];
    int inc = x;
    #pragma unroll
    for (int d = 1; d < 64; d <<= 1) {
      int o = __shfl_up(inc, d, 64);
      if (lane >= d) inc += o;
    }
    if (lane == 63) wsum[wave] = inc;
    __syncthreads();
    int wbase = 0;
    #pragma unroll
    for (int w = 0; w < 4; ++w)
      if (w < wave) wbase += wsum[w];
    int excl = wbase + inc - x;
    __syncthreads();
    sh[t] = base + excl;
  }
  __syncthreads();
  const int node0 = r << NBBITS;
  {
    int g = node0 + t;
    if (g < N) offsets[g] = sh[t];
  }
  if (r == NB - 1 && t == 0) offsets[N] = E;
  __syncthreads();
  for (int i = base + t; i < endr; i += 256) {
    unsigned v = packed[i];
    int pos = atomicAdd(&sh[v & (BKNODES - 1)], 1);
    edgeSrc[pos] = (int)(v >> NBBITS);
  }
}

// ---------------------------------------------------------------------------
// Grid-stride persistent-wave aggregate (unchanged from R7, measured 70 us).
// ---------------------------------------------------------------------------
__global__ __launch_bounds__(256) void aggregate(const ushort* __restrict__ zb,
                                                 const float* __restrict__ df,
                                                 const int* __restrict__ offsets,
                                                 const int* __restrict__ edgeSrc,
                                                 float* __restrict__ out, int N, int NW) {
  const int lane = threadIdx.x & 63;
  int d = __builtin_amdgcn_readfirstlane((int)((blockIdx.x * blockDim.x + threadIdx.x) >> 6));
  if (d >= N) return;
  const int g = lane >> 4;
  const int l16 = lane & 15;

  int beg = offsets[d];
  int end = offsets[d + 1];
  float4 df4 = *(const float4*)(df + (size_t)d * 64 + l16 * 4);

  while (true) {
    const int nd = d + NW;
    const int ndc = min(nd, N - 1);
    const int nbeg = offsets[ndc];
    const int nend = offsets[ndc + 1];
    const float4 ndf4 = *(const float4*)(df + (size_t)ndc * 64 + l16 * 4);

    float m = -INFINITY, l = 0.f;
    float ax = 0.f, ay = 0.f, az = 0.f, aw = 0.f;

    for (int j0 = beg; j0 < end; j0 += 32) {
      const int nst = min(8, (end - j0 + 3) >> 2);
      uint2 zf[8];
      float ew[8];
      float bm = -INFINITY;

      #pragma unroll
      for (int st = 0; st < 8; ++st) {
        if (st < nst) {
          const int eidx = j0 + st * 4 + g;
          const bool act = eidx < end;
          int s = 0;
          if (act) s = edgeSrc[eidx];
          zf[st] = *(const uint2*)(zb + (size_t)s * 64 + l16 * 4);
          float p = bf_lo(zf[st].x) * df4.x;
          p = fmaf(bf_hi(zf[st].x), df4.y, p);
          p = fmaf(bf_lo(zf[st].y), df4.z, p);
          p = fmaf(bf_hi(zf[st].y), df4.w, p);
          p += __shfl_xor(p, 1, 64);
          p += __shfl_xor(p, 2, 64);
          p += __shfl_xor(p, 4, 64);
          p += __shfl_xor(p, 8, 64);
          ew[st] = act ? p : -INFINITY;
          bm = fmaxf(bm, ew[st]);
        }
      }
      bm = fmaxf(bm, __shfl_xor(bm, 16, 64));
      bm = fmaxf(bm, __shfl_xor(bm, 32, 64));

      const float nm = fmaxf(m, bm);
      const float alpha = __expf(m - nm);
      float sw = 0.f;
      #pragma unroll
      for (int st = 0; st < 8; ++st) {
        if (st < nst) {
          const float w = __expf(ew[st] - nm);
          ew[st] = w;
          sw += w;
        }
      }
      sw += __shfl_xor(sw, 16, 64);
      sw += __shfl_xor(sw, 32, 64);
      l = l * alpha + sw;
      m = nm;

      ax *= alpha; ay *= alpha; az *= alpha; aw *= alpha;
      #pragma unroll
      for (int st = 0; st < 8; ++st) {
        if (st < nst) {
          const float w = ew[st];
          ax = fmaf(w, bf_lo(zf[st].x), ax);
          ay = fmaf(w, bf_hi(zf[st].x), ay);
          az = fmaf(w, bf_lo(zf[st].y), az);
          aw = fmaf(w, bf_hi(zf[st].y), aw);
        }
      }
    }

    ax += __shfl_xor(ax, 16, 64); ax += __shfl_xor(ax, 32, 64);
    ay += __shfl_xor(ay, 16, 64); ay += __shfl_xor(ay, 32, 64);
    az += __shfl_xor(az, 16, 64); az += __shfl_xor(az, 32, 64);
    aw += __shfl_xor(aw, 16, 64); aw += __shfl_xor(aw, 32, 64);

    if (lane < 16) {
      const float inv = (l > 0.f) ? (1.f / l) : 0.f;
      float4 o;
      o.x = ax * inv; o.y = ay * inv; o.z = az * inv; o.w = aw * inv;
      *(float4*)(out + (size_t)d * 64 + l16 * 4) = o;
    }

    if (nd >= N) break;
    d = nd; beg = nbeg; end = nend; df4 = ndf4;
  }
}

// ---------------------------------------------------------------------------
extern "C" void kernel_launch(void* const* d_in, const int* in_sizes, int n_in,
                              void* d_out, int out_size, void* d_ws, size_t ws_size,
                              hipStream_t stream) {
  const float* h     = (const float*)d_in[0];  // [N,256]
  const float* feat  = (const float*)d_in[1];  // [N,64]
  const float* W_fc  = (const float*)d_in[2];  // [64,256]
  const float* W_dst = (const float*)d_in[3];  // [64,64]
  const int*   src   = (const int*)d_in[4];    // [E]
  const int*   dst   = (const int*)d_in[5];    // [E]
  float* out = (float*)d_out;

  const int N = in_sizes[1] / 64;        // 100000
  const int E = in_sizes[4];             // 1600000

  const int NB = (N + BKNODES - 1) >> NBBITS;  // 391 buckets
  const int nChunks = (E + CH - 1) / CH;       // 391

  // workspace layout
  char* ws = (char*)d_ws;
  ushort* zb = (ushort*)ws;                        // N*64 bf16
  float* df = (float*)(zb + (size_t)N * 64);       // N*64 f32
  int* offsets = (int*)(df + (size_t)N * 64);      // N+1
  int* edgeSrc = offsets + N + 1;                  // E
  int* bCnt = edgeSrc + E;                         // NB
  int* relCur = bCnt + NB;                         // NB (contiguous with bCnt)
  // packed scratch lives in d_out (E u32 <= N*64 f32), consumed before aggregate
  unsigned* packed = (unsigned*)d_out;

  hipMemsetAsync(bCnt, 0, sizeof(int) * (size_t)(2 * NB), stream);

  const int gsplit = (N + 127) / 128;  // 782
  gemm_count<<<nChunks + gsplit * 2, 256, 0, stream>>>(h, feat, W_fc, W_dst, zb, df,
                                                       dst, bCnt, N, gsplit, E, NB,
                                                       nChunks);

  csr_partition<<<nChunks, 256, 0, stream>>>(src, dst, bCnt, relCur, packed, E, NB);
  csr_finalize<<<NB, 256, 0, stream>>>(bCnt, packed, edgeSrc, offsets, N, NB, E);

  // persistent-wave aggregate: 2048 blocks x 4 waves = 8192 waves
  const int aggBlocks = 2048;
  const int NW = aggBlocks * 4;
  aggregate<<<aggBlocks, 256, 0, stream>>>(zb, df, offsets, edgeSrc, out, N, NW);
}